// Round 19
// baseline (2399.639 us; speedup 1.0000x reference)
//
#include <hip/hip_runtime.h>
#include <cstdint>
#include <cstddef>

#define T_TOK 2048
#define HIDN  2048
#define NHEAD 16
#define QLRr  1536
#define KVLRr 512
#define DNn   128
#define DRr   64
#define DVv   128
#define QKDd  192
#define INHh  16
#define IHDd  128
#define ITOPKk 512
#define NEXP  8
#define MIi   512
#define SHMI  1024
#define EPSF  1e-6f
#define NEGINF (-3.402823466e38f)

typedef __attribute__((ext_vector_type(8))) short short8;
typedef __attribute__((ext_vector_type(4))) float float4v;

// ---------------- helpers ----------------
__device__ __forceinline__ float warp_sum(float v){
#pragma unroll
  for (int off=32; off>0; off>>=1) v += __shfl_down(v, off, 64);
  return v;
}
__device__ __forceinline__ float warp_max(float v){
#pragma unroll
  for (int off=32; off>0; off>>=1) v = fmaxf(v, __shfl_down(v, off, 64));
  return v;
}
__device__ __forceinline__ unsigned mapf(float f){
  unsigned b = __float_as_uint(f);
  if ((b<<1)==0u) b = 0u;
  return (b & 0x80000000u) ? ~b : (b | 0x80000000u);
}
__device__ __forceinline__ ushort f2bf(float f){
  unsigned u = __float_as_uint(f);
  unsigned r = (u + 0x7fffu + ((u>>16)&1u)) >> 16;
  return (ushort)r;
}
__device__ __forceinline__ float bf2f(ushort u){
  return __uint_as_float(((unsigned)u) << 16);
}
// async global->LDS, 16B per lane; LDS dest = wave-uniform base + lane*16
__device__ __forceinline__ void gload16(const ushort* g, ushort* l){
  __builtin_amdgcn_global_load_lds((const __attribute__((address_space(1))) void*)g,
                                   (__attribute__((address_space(3))) void*)l, 16, 0, 0);
}

// ---------------- rope tables ----------------
__global__ void rope_table_kernel(const int* __restrict__ pos,
                                  float* __restrict__ ct, float* __restrict__ st){
  int t = blockIdx.x, j = threadIdx.x;          // blockDim 32
  float inv = powf(10000.0f, -(float)j * (1.0f/32.0f));
  float f = (float)pos[t] * inv;
  ct[t*32+j] = cosf(f);
  st[t*32+j] = sinf(f);
}

// ---------------- rmsnorm (fp32 out) ----------------
__global__ __launch_bounds__(256) void rmsnorm_kernel(
    const float* __restrict__ x, int xstride, int xoff,
    const float* __restrict__ w, float* __restrict__ out, int ostride, int D){
  int t = blockIdx.x, tid = threadIdx.x;
  const float* xp = x + (size_t)t*xstride + xoff;
  const float4* x4 = (const float4*)xp;
  int D4 = D >> 2;
  float ss = 0.f;
  for (int i = tid; i < D4; i += 256){ float4 v = x4[i]; ss += v.x*v.x+v.y*v.y+v.z*v.z+v.w*v.w; }
  __shared__ float red[4];
  float s = warp_sum(ss);
  int lane = tid & 63, wid = tid >> 6;
  if (lane==0) red[wid] = s;
  __syncthreads();
  if (tid==0) red[0] = red[0]+red[1]+red[2]+red[3];
  __syncthreads();
  float sc = rsqrtf(red[0]/(float)D + EPSF);
  const float4* w4 = (const float4*)w;
  float4* o4 = (float4*)(out + (size_t)t*ostride);
  for (int i = tid; i < D4; i += 256){
    float4 v = x4[i], ww = w4[i];
    float4 r; r.x=v.x*sc*ww.x; r.y=v.y*sc*ww.y; r.z=v.z*sc*ww.z; r.w=v.w*sc*ww.w;
    o4[i] = r;
  }
}

// ---------------- rmsnorm emitting split hi/lo bf16 directly ----------------
__global__ __launch_bounds__(256) void rmsnorm_split(
    const float* __restrict__ x, int xstride, int xoff,
    const float* __restrict__ w, ushort* __restrict__ hi, ushort* __restrict__ lo,
    int ostride, int D){
  int t = blockIdx.x, tid = threadIdx.x;
  const float* xp = x + (size_t)t*xstride + xoff;
  const float4* x4 = (const float4*)xp;
  int D4 = D >> 2;
  float ss = 0.f;
  for (int i = tid; i < D4; i += 256){ float4 v = x4[i]; ss += v.x*v.x+v.y*v.y+v.z*v.z+v.w*v.w; }
  __shared__ float red[4];
  float s = warp_sum(ss);
  int lane = tid & 63, wid = tid >> 6;
  if (lane==0) red[wid] = s;
  __syncthreads();
  if (tid==0) red[0] = red[0]+red[1]+red[2]+red[3];
  __syncthreads();
  float sc = rsqrtf(red[0]/(float)D + EPSF);
  const float4* w4 = (const float4*)w;
  ushort4* h4 = (ushort4*)(hi + (size_t)t*ostride);
  ushort4* l4 = (ushort4*)(lo + (size_t)t*ostride);
  for (int i = tid; i < D4; i += 256){
    float4 v = x4[i], ww = w4[i];
    float4 r; r.x=v.x*sc*ww.x; r.y=v.y*sc*ww.y; r.z=v.z*sc*ww.z; r.w=v.w*sc*ww.w;
    ushort4 hh, ll;
    hh.x = f2bf(r.x); ll.x = f2bf(r.x - bf2f(hh.x));
    hh.y = f2bf(r.y); ll.y = f2bf(r.y - bf2f(hh.y));
    hh.z = f2bf(r.z); ll.z = f2bf(r.z - bf2f(hh.z));
    hh.w = f2bf(r.w); ll.w = f2bf(r.w - bf2f(hh.w));
    h4[i] = hh; l4[i] = ll;
  }
}

// ---------------- k_pe rope (fp32 out) ----------------
__global__ void rope_kpe_kernel(const float* __restrict__ pe,
                                const float* __restrict__ ct, const float* __restrict__ st,
                                float* __restrict__ kpe){
  int t = blockIdx.x, j = threadIdx.x;          // blockDim 32
  const float* x = pe + (size_t)t*64;
  float x1 = x[j], x2 = x[32+j];
  float c = ct[t*32+j], sn = st[t*32+j];
  kpe[t*64+j]    = x1*c - x2*sn;
  kpe[t*64+32+j] = x1*sn + x2*c;
}

// ---------------- idx_k layernorm + rope, emitting split hi/lo ------------
__global__ __launch_bounds__(128) void ln_rope_idxk_split(
    const float* __restrict__ xk, const float* __restrict__ w, const float* __restrict__ b,
    const float* __restrict__ ct, const float* __restrict__ st,
    ushort* __restrict__ hi, ushort* __restrict__ lo){
  int t = blockIdx.x, tid = threadIdx.x;
  float v = xk[(size_t)t*IHDd + tid];
  float s1 = warp_sum(v), s2 = warp_sum(v*v);
  __shared__ float r1[2], r2[2];
  int lane = tid & 63, wid = tid >> 6;
  if (lane==0){ r1[wid]=s1; r2[wid]=s2; }
  __syncthreads();
  float mean = (r1[0]+r1[1]) * (1.f/128.f);
  float var  = (r2[0]+r2[1]) * (1.f/128.f) - mean*mean;
  float y = (v-mean)*rsqrtf(var+EPSF)*w[tid]+b[tid];
  __shared__ float ly[128];
  ly[tid] = y; __syncthreads();
  float o;
  if (tid < 64) o = y;
  else if (tid < 96){ int j = tid-64; o = ly[64+j]*ct[t*32+j] - ly[96+j]*st[t*32+j]; }
  else              { int j = tid-96; o = ly[64+j]*st[t*32+j] + ly[96+j]*ct[t*32+j]; }
  ushort hh = f2bf(o);
  hi[(size_t)t*IHDd + tid] = hh;
  lo[(size_t)t*IHDd + tid] = f2bf(o - bf2f(hh));
}

// ---------------- rope over q ----------------
__global__ __launch_bounds__(256) void rope_q_kernel(float* __restrict__ q,
                                  const float* __restrict__ ct, const float* __restrict__ st){
  int t = blockIdx.x, tid = threadIdx.x;
  __shared__ float c[32], s[32];
  if (tid < 32){ c[tid]=ct[t*32+tid]; s[tid]=st[t*32+tid]; }
  __syncthreads();
  for (int idx = tid; idx < NHEAD*32; idx += 256){
    int hh = idx >> 5, j = idx & 31;
    float* base = q + (size_t)t*(NHEAD*QKDd) + hh*QKDd;
    float x1 = base[DNn+j], x2 = base[DNn+32+j];
    base[DNn+j]    = x1*c[j] - x2*s[j];
    base[DNn+32+j] = x1*s[j] + x2*c[j];
  }
}

// ---------------- rope over idx_q, emitting split hi/lo ----------------
__global__ __launch_bounds__(256) void rope_idxq_split(const float* __restrict__ q,
                                  const float* __restrict__ ct, const float* __restrict__ st,
                                  ushort* __restrict__ hi, ushort* __restrict__ lo){
  int t = blockIdx.x, tid = threadIdx.x;
  __shared__ float c[32], s[32];
  if (tid < 32){ c[tid]=ct[t*32+tid]; s[tid]=st[t*32+tid]; }
  __syncthreads();
  const float* row = q + (size_t)t*2048;
  for (int idx = tid; idx < 2048; idx += 256){
    int d = idx & 127; int base = idx - d;
    float v;
    if (d < 64) v = row[idx];
    else if (d < 96){ int j = d-64; v = row[base+64+j]*c[j] - row[base+96+j]*s[j]; }
    else            { int j = d-96; v = row[base+64+j]*s[j] + row[base+96+j]*c[j]; }
    ushort hh = f2bf(v);
    hi[(size_t)t*2048 + idx] = hh;
    lo[(size_t)t*2048 + idx] = f2bf(v - bf2f(hh));
  }
}

// ---------------- fp32 GEMM, 64x64 tile (small N only) ----------------
__global__ __launch_bounds__(256) void gemm_f32(
    const float* __restrict__ A, int lda,
    const float* __restrict__ B, int ldb,
    float* __restrict__ C, int ldc,
    const float* __restrict__ addsrc, int ldadd,
    int M, int N, int K, float alpha){
  __shared__ float As[16][68];
  __shared__ float Bs[16][68];
  int tid = threadIdx.x;
  int tx = tid & 15, ty = tid >> 4;
  int m0 = blockIdx.y*64, n0 = blockIdx.x*64;
  float acc[4][4] = {};
  for (int k0 = 0; k0 < K; k0 += 16){
#pragma unroll
    for (int i = 0; i < 4; i++){
      int lin = tid + i*256; int r = lin >> 4, c = lin & 15;
      int m = m0 + r;
      As[c][r] = (m < M) ? A[(size_t)m*lda + k0 + c] : 0.f;
    }
#pragma unroll
    for (int i = 0; i < 4; i++){
      int lin = tid + i*256; int kk = lin >> 6, c = lin & 63;
      int n = n0 + c;
      Bs[kk][c] = (n < N) ? B[(size_t)(k0+kk)*ldb + n] : 0.f;
    }
    __syncthreads();
#pragma unroll
    for (int kk = 0; kk < 16; kk++){
      float4 av = *(const float4*)&As[kk][ty*4];
      float4 bv = *(const float4*)&Bs[kk][tx*4];
      float a[4] = {av.x, av.y, av.z, av.w};
      float b[4] = {bv.x, bv.y, bv.z, bv.w};
#pragma unroll
      for (int i = 0; i < 4; i++)
#pragma unroll
        for (int j = 0; j < 4; j++) acc[i][j] += a[i]*b[j];
    }
    __syncthreads();
  }
#pragma unroll
  for (int i = 0; i < 4; i++){
    int m = m0 + ty*4 + i;
    if (m >= M) continue;
#pragma unroll
    for (int j = 0; j < 4; j++){
      int n = n0 + tx*4 + j;
      if (n >= N) continue;
      float v = acc[i][j]*alpha;
      if (addsrc) v += addsrc[(size_t)m*ldadd + n];
      C[(size_t)m*ldc + n] = v;
    }
  }
}

// ---------------- convert fp32 -> bf16 ----------------
__global__ __launch_bounds__(256) void conv_bf16(const float* __restrict__ in,
                                                 ushort* __restrict__ out, int n4){
  int i = blockIdx.x*256 + threadIdx.x;
  if (i < n4){
    float4 v = ((const float4*)in)[i];
    ushort4 o; o.x=f2bf(v.x); o.y=f2bf(v.y); o.z=f2bf(v.z); o.w=f2bf(v.w);
    ((ushort4*)out)[i] = o;
  }
}

// ---------------- split fp32 -> (hi, lo) bf16 pair ----------------
__global__ __launch_bounds__(256) void split_bf16(const float* __restrict__ in,
                                                  ushort* __restrict__ hi,
                                                  ushort* __restrict__ lo, int n4){
  int i = blockIdx.x*256 + threadIdx.x;
  if (i >= n4) return;
  float4 v = ((const float4*)in)[i];
  ushort4 h, l;
  h.x = f2bf(v.x); l.x = f2bf(v.x - bf2f(h.x));
  h.y = f2bf(v.y); l.y = f2bf(v.y - bf2f(h.y));
  h.z = f2bf(v.z); l.z = f2bf(v.z - bf2f(h.z));
  h.w = f2bf(v.w); l.w = f2bf(v.w - bf2f(h.w));
  ((ushort4*)hi)[i] = h;
  ((ushort4*)lo)[i] = l;
}

// ---------------- transpose + convert: src[K,N] fp32 -> dst[N,K] bf16 ----------------
__global__ __launch_bounds__(256) void transconv(const float* __restrict__ src0,
                                                 ushort* __restrict__ dst0, int K, int N){
  int e = blockIdx.z;
  const float* src = src0 + (size_t)e*K*N;
  ushort* dst = dst0 + (size_t)e*N*K;
  int k0 = blockIdx.y*32, n0 = blockIdx.x*32;
  __shared__ float tile[32][33];
  int c = threadIdx.x & 31, r = threadIdx.x >> 5;
  for (int rr = r; rr < 32; rr += 8) tile[rr][c] = src[(size_t)(k0+rr)*N + n0 + c];
  __syncthreads();
  for (int rr = r; rr < 32; rr += 8) dst[(size_t)(n0+rr)*K + k0 + c] = f2bf(tile[c][rr]);
}

// ---------------- transpose + split: src[K,N] fp32 -> hi/lo [N,K] bf16 ----------------
__global__ __launch_bounds__(256) void transconv_split(const float* __restrict__ src,
                                                       ushort* __restrict__ dhi,
                                                       ushort* __restrict__ dlo, int K, int N){
  int k0 = blockIdx.y*32, n0 = blockIdx.x*32;
  __shared__ float tile[32][33];
  int c = threadIdx.x & 31, r = threadIdx.x >> 5;
  for (int rr = r; rr < 32; rr += 8) tile[rr][c] = src[(size_t)(k0+rr)*N + n0 + c];
  __syncthreads();
  for (int rr = r; rr < 32; rr += 8){
    float x = tile[c][rr];
    ushort h = f2bf(x);
    ushort l = f2bf(x - bf2f(h));
    size_t o = (size_t)(n0+rr)*K + k0 + c;
    dhi[o] = h; dlo[o] = l;
  }
}

// ===== split-bf16 (Markidis) MFMA GEMM via global_load_lds (m97 style) =====
// LDS tiles are linear [128][32] ushorts; each wave DMAs 1KB per call
// (lane l's 16B from row w*32+k*16+(l>>2), quarter l&3 -> LDS base+(l*16)).
__global__ __launch_bounds__(256) void gemm_b3(
    const ushort* __restrict__ Ah, const ushort* __restrict__ Al,
    const ushort* __restrict__ Bh, const ushort* __restrict__ Bl,
    float* __restrict__ C, const float* __restrict__ addsrc, int N, int K){
  __shared__ __align__(16) ushort Ahs[4096], Als[4096];
  __shared__ __align__(16) ushort Bhs[4096], Bls[4096];
  int tid = threadIdx.x, lane = tid & 63, w = tid >> 6;
  int m0 = blockIdx.y*128, n0 = blockIdx.x*128;
  int wr = w >> 1, wc = w & 1;
  int r15 = lane & 15, g = lane >> 4;
  // staging source rows (two calls per buffer)
  int row0 = w*32 + (lane>>2);
  int row1 = row0 + 16;
  int qq = (lane & 3) * 8;                   // ushort offset within 32-elem row chunk
  const ushort* a0p = Ah + (size_t)(m0+row0)*K + qq;
  const ushort* a1p = Ah + (size_t)(m0+row1)*K + qq;
  const ushort* al0p = Al + (size_t)(m0+row0)*K + qq;
  const ushort* al1p = Al + (size_t)(m0+row1)*K + qq;
  const ushort* b0p = Bh + (size_t)(n0+row0)*K + qq;
  const ushort* b1p = Bh + (size_t)(n0+row1)*K + qq;
  const ushort* bl0p = Bl + (size_t)(n0+row0)*K + qq;
  const ushort* bl1p = Bl + (size_t)(n0+row1)*K + qq;
  // LDS dest bases (wave-uniform)
  int d0 = (w*2+0)*512, d1 = (w*2+1)*512;
  int aoff[4], boff[4];
#pragma unroll
  for (int m = 0; m < 4; m++){
    aoff[m] = (wr*64 + m*16 + r15)*32 + g*8;
    boff[m] = (wc*64 + m*16 + r15)*32 + g*8;
  }
  float4v acc[4][4];
#pragma unroll
  for (int i=0;i<4;i++)
#pragma unroll
    for (int j=0;j<4;j++) acc[i][j] = (float4v){0.f,0.f,0.f,0.f};
  int nk = K >> 5;
  for (int kt = 0; kt < nk; kt++){
    int k0 = kt << 5;
    __syncthreads();
    gload16(a0p + k0, &Ahs[d0]);  gload16(a1p + k0, &Ahs[d1]);
    gload16(al0p + k0, &Als[d0]); gload16(al1p + k0, &Als[d1]);
    gload16(b0p + k0, &Bhs[d0]);  gload16(b1p + k0, &Bhs[d1]);
    gload16(bl0p + k0, &Bls[d0]); gload16(bl1p + k0, &Bls[d1]);
    __syncthreads();
    short8 avh[4], avl[4], bvh[4], bvl[4];
#pragma unroll
    for (int m = 0; m < 4; m++){
      avh[m] = *(const short8*)&Ahs[aoff[m]];
      avl[m] = *(const short8*)&Als[aoff[m]];
    }
#pragma unroll
    for (int n = 0; n < 4; n++){
      bvh[n] = *(const short8*)&Bhs[boff[n]];
      bvl[n] = *(const short8*)&Bls[boff[n]];
    }
#pragma unroll
    for (int m = 0; m < 4; m++)
#pragma unroll
      for (int n = 0; n < 4; n++){
        acc[m][n] = __builtin_amdgcn_mfma_f32_16x16x32_bf16(avh[m], bvh[n], acc[m][n], 0, 0, 0);
        acc[m][n] = __builtin_amdgcn_mfma_f32_16x16x32_bf16(avl[m], bvh[n], acc[m][n], 0, 0, 0);
        acc[m][n] = __builtin_amdgcn_mfma_f32_16x16x32_bf16(avh[m], bvl[n], acc[m][n], 0, 0, 0);
      }
  }
#pragma unroll
  for (int m = 0; m < 4; m++){
    int row0c = m0 + wr*64 + m*16 + g*4;
#pragma unroll
    for (int n = 0; n < 4; n++){
      int col = n0 + wc*64 + n*16 + r15;
#pragma unroll
      for (int r = 0; r < 4; r++){
        float v = acc[m][n][r];
        size_t o = (size_t)(row0c + r)*N + col;
        if (addsrc) v += addsrc[o];
        C[o] = v;
      }
    }
  }
}

// ===== indexer scores via split-bf16 MFMA, triangular 128x128 tiles =====
__global__ __launch_bounds__(256) void iscores_b3(
    const ushort* __restrict__ iqh, const ushort* __restrict__ iql,  // [T,16,128]
    const ushort* __restrict__ ikh, const ushort* __restrict__ ikl,  // [T,128]
    const float* __restrict__ idx_w,                                 // [T,16]
    float* __restrict__ sc){                                         // [T,T]
  int sb = blockIdx.x, tb = blockIdx.y;
  if (sb > tb) return;
  int t0 = tb*128, s0 = sb*128;
  __shared__ __align__(16) ushort Ahs[5120], Als[5120];
  __shared__ __align__(16) ushort Bhs[5120], Bls[5120];
  __shared__ float wlds[128][17];
  int tid = threadIdx.x, lane = tid & 63, w = tid >> 6;
  int wr = w >> 1, wc = w & 1;
  int r15 = lane & 15, g = lane >> 4;
  int srow = tid >> 1, sh = (tid & 1) << 4;
  for (int i = tid; i < 2048; i += 256){
    int r = i >> 4, hh = i & 15;
    wlds[r][hh] = idx_w[(size_t)(t0+r)*16 + hh];
  }
  int soff = srow*40 + sh;
  int aoff[4], boff[4];
#pragma unroll
  for (int m = 0; m < 4; m++){
    aoff[m] = (wr*64 + m*16 + r15)*40 + g*8;
    boff[m] = (wc*64 + m*16 + r15)*40 + g*8;
  }
  float4v sco[4][4];
#pragma unroll
  for (int i=0;i<4;i++)
#pragma unroll
    for (int j=0;j<4;j++) sco[i][j] = (float4v){0.f,0.f,0.f,0.f};
  for (int h = 0; h < 16; h++){
    float4v acc[4][4];
#pragma unroll
    for (int i=0;i<4;i++)
#pragma unroll
      for (int j=0;j<4;j++) acc[i][j] = (float4v){0.f,0.f,0.f,0.f};
    size_t arow = ((size_t)(t0 + srow)*16 + h)*128 + sh;
    size_t brow = (size_t)(s0 + srow)*128 + sh;
    short8 ah0 = *(const short8*)(iqh + arow);
    short8 ah1 = *(const short8*)(iqh + arow + 8);
    short8 al0 = *(const short8*)(iql + arow);
    short8 al1 = *(const short8*)(iql + arow + 8);
    short8 bh0 = *(const short8*)(ikh + brow);
    short8 bh1 = *(const short8*)(ikh + brow + 8);
    short8 bl0 = *(const short8*)(ikl + brow);
    short8 bl1 = *(const short8*)(ikl + brow + 8);
    for (int kt = 0; kt < 4; kt++){
      __syncthreads();
      *(short8*)&Ahs[soff] = ah0; *(short8*)&Ahs[soff+8] = ah1;
      *(short8*)&Als[soff] = al0; *(short8*)&Als[soff+8] = al1;
      *(short8*)&Bhs[soff] = bh0; *(short8*)&Bhs[soff+8] = bh1;
      *(short8*)&Bls[soff] = bl0; *(short8*)&Bls[soff+8] = bl1;
      __syncthreads();
      if (kt < 3){
        int k0 = (kt+1) << 5;
        ah0 = *(const short8*)(iqh + arow + k0);
        ah1 = *(const short8*)(iqh + arow + k0 + 8);
        al0 = *(const short8*)(iql + arow + k0);
        al1 = *(const short8*)(iql + arow + k0 + 8);
        bh0 = *(const short8*)(ikh + brow + k0);
        bh1 = *(const short8*)(ikh + brow + k0 + 8);
        bl0 = *(const short8*)(ikl + brow + k0);
        bl1 = *(const short8*)(ikl + brow + k0 + 8);
      }
      short8 avh[4], avl[4], bvh[4], bvl[4];
#pragma unroll
      for (int m = 0; m < 4; m++){
        avh[m] = *(const short8*)&Ahs[aoff[m]];
        avl[m] = *(const short8*)&Als[aoff[m]];
      }
#pragma unroll
      for (int n = 0; n < 4; n++){
        bvh[n] = *(const short8*)&Bhs[boff[n]];
        bvl[n] = *(const short8*)&Bls[boff[n]];
      }
#pragma unroll
      for (int m = 0; m < 4; m++)
#pragma unroll
        for (int n = 0; n < 4; n++){
          acc[m][n] = __builtin_amdgcn_mfma_f32_16x16x32_bf16(avh[m], bvh[n], acc[m][n], 0, 0, 0);
          acc[m][n] = __builtin_amdgcn_mfma_f32_16x16x32_bf16(avl[m], bvh[n], acc[m][n], 0, 0, 0);
          acc[m][n] = __builtin_amdgcn_mfma_f32_16x16x32_bf16(avh[m], bvl[n], acc[m][n], 0, 0, 0);
        }
    }
#pragma unroll
    for (int m = 0; m < 4; m++){
      int rbase = wr*64 + m*16 + g*4;
#pragma unroll
      for (int r = 0; r < 4; r++){
        float wv = wlds[rbase + r][h];
#pragma unroll
        for (int n = 0; n < 4; n++)
          sco[m][n][r] += wv * fmaxf(acc[m][n][r], 0.f);
      }
    }
  }
#pragma unroll
  for (int m = 0; m < 4; m++){
    int row0 = t0 + wr*64 + m*16 + g*4;
#pragma unroll
    for (int n = 0; n < 4; n++){
      int col = s0 + wc*64 + n*16 + r15;
#pragma unroll
      for (int r = 0; r < 4; r++)
        sc[(size_t)(row0 + r)*2048 + col] = sco[m][n][r];
    }
  }
}

// ===== reg-staged bf16 MFMA GEMM with register prefetch =====
template<int OUTBF>
__global__ __launch_bounds__(256) void gemm_bf16s(
    const ushort* __restrict__ A, const ushort* __restrict__ Bt,
    float* __restrict__ Cf, ushort* __restrict__ Cb,
    const float* __restrict__ addsrc, int N, int K){
  __shared__ __align__(16) ushort As[5120];
  __shared__ __align__(16) ushort Bs[5120];
  int tid = threadIdx.x, lane = tid & 63, w = tid >> 6;
  int m0 = blockIdx.y*128, n0 = blockIdx.x*128;
  int wr = w >> 1, wc = w & 1;
  int r15 = lane & 15, g = lane >> 4;
  int srow = tid >> 1, sh = (tid & 1) << 4;
  const ushort* Ag = A + (size_t)(m0 + srow)*K + sh;
  const ushort* Bg = Bt + (size_t)(n0 + srow)*K + sh;
  ushort* Asw = &As[srow*40 + sh];
  ushort* Bsw = &Bs[srow*40 + sh];
  int aoff[4], boff[4];
#pragma unroll
  for (int m = 0; m < 4; m++){
    aoff[m] = (wr*64 + m*16 + r15)*40 + g*8;
    boff[m] = (wc*64 + m*16 + r15)*40 + g*8;
  }
  float4v acc[4][4];
#pragma unroll
  for (int i=0;i<4;i++)
#pragma unroll
    for (int j=0;j<4;j++) acc[i][j] = (float4v){0.f,0.f,0.f,0.f};
  int nk = K >> 5;
  short8 a0 = *(const short8*)(Ag);
  short8 a1 = *(const short8*)(Ag + 8);
  short8 b0 = *(const short8*)(Bg);
  short8 b1 = *(const short8*)(Bg + 8);
  for (int kt = 0; kt < nk; kt++){
    __syncthreads();
    *(short8*)Asw = a0; *(short8*)(Asw + 8) = a1;
    *(short8*)Bsw = b0; *(short8*)(Bsw + 8) = b1;
    __syncthreads();
    if (kt+1 < nk){
      int k0 = (kt+1) << 5;
      a0 = *(const short8*)(Ag + k0);
      a1 = *(const short8*)(Ag + k0 + 8);
      b0 = *(const short8*)(Bg + k0);
      b1 = *(const short8*)(Bg + k0 + 8);
    }
    short8 av[4], bv[4];
#pragma unroll
    for (int m = 0; m < 4; m++) av[m] = *(const short8*)&As[aoff[m]];
#pragma unroll
    for (int n = 0; n < 4; n++) bv[n] = *(const short8*)&Bs[boff[n]];
#pragma unroll
    for (int m = 0; m < 4; m++)
#pragma unroll
      for (int n = 0; n < 4; n++)
        acc[m][n] = __builtin_amdgcn_mfma_f32_16x16x32_bf16(av[m], bv[n], acc[m][n], 0, 0, 0);
  }
#pragma unroll
  for (int m = 0; m < 4; m++){
    int row0 = m0 + wr*64 + m*16 + g*4;
#pragma unroll
    for (int n = 0; n < 4; n++){
      int col = n0 + wc*64 + n*16 + r15;
#pragma unroll
      for (int r = 0; r < 4; r++){
        float v = acc[m][n][r];
        size_t o = (size_t)(row0 + r)*N + col;
        if (addsrc) v += addsrc[o];
        if (OUTBF) Cb[o] = f2bf(v);
        else       Cf[o] = v;
      }
    }
  }
}

// ===== MoE GEMM1 (gathered rows of h2_bf) -> gu fp32, prefetch =====
__global__ __launch_bounds__(256) void moe_gemm1s(
    const ushort* __restrict__ h2bf, const ushort* __restrict__ wgut,
    const int* __restrict__ ecnt, const int* __restrict__ elist,
    float* __restrict__ gu){
  int e = blockIdx.z;
  int count = ecnt[e];
  int r0 = blockIdx.y*128;
  if (r0 >= count) return;
  __shared__ int rows[128];
  __shared__ __align__(16) ushort As[5120];
  __shared__ __align__(16) ushort Bs[5120];
  int tid = threadIdx.x, lane = tid & 63, w = tid >> 6;
  int n0 = blockIdx.x*128;
  if (tid < 128) rows[tid] = (r0 + tid < count) ? elist[e*2048 + r0 + tid] : -1;
  __syncthreads();
  int wr = w >> 1, wc = w & 1;
  int r15 = lane & 15, g = lane >> 4;
  int srow = tid >> 1, sh = (tid & 1) << 4;
  int ent0 = rows[srow];
  int tok = (ent0 >= 0) ? (ent0 >> 2) : 0;
  const ushort* Ag = h2bf + (size_t)tok*2048 + sh;
  const ushort* Bg = wgut + ((size_t)e*1024 + n0 + srow)*2048 + sh;
  ushort* Asw = &As[srow*40 + sh];
  ushort* Bsw = &Bs[srow*40 + sh];
  int aoff[4], boff[4];
#pragma unroll
  for (int m = 0; m < 4; m++){
    aoff[m] = (wr*64 + m*16 + r15)*40 + g*8;
    boff[m] = (wc*64 + m*16 + r15)*40 + g*8;
  }
  float4v acc[4][4];
#pragma unroll
  for (int i=0;i<4;i++)
#pragma unroll
    for (int j=0;j<4;j++) acc[i][j] = (float4v){0.f,0.f,0.f,0.f};
  short8 a0 = *(const short8*)(Ag);
  short8 a1 = *(const short8*)(Ag + 8);
  short8 b0 = *(const short8*)(Bg);
  short8 b1 = *(const short8*)(Bg + 8);
  for (int kt = 0; kt < 64; kt++){
    __syncthreads();
    *(short8*)Asw = a0; *(short8*)(Asw + 8) = a1;
    *(short8*)Bsw = b0; *(short8*)(Bsw + 8) = b1;
    __syncthreads();
    if (kt < 63){
      int k0 = (kt+1) << 5;
      a0 = *(const short8*)(Ag + k0);
      a1 = *(const short8*)(Ag + k0 + 8);
      b0 = *(const short8*)(Bg + k0);
      b1 = *(const short8*)(Bg + k0 + 8);
    }
    short8 av[4], bv[4];
#pragma unroll
    for (int m = 0; m < 4; m++) av[m] = *(const short8*)&As[aoff[m]];
#pragma unroll
    for (int n = 0; n < 4; n++) bv[n] = *(const short8*)&Bs[boff[n]];
#pragma unroll
    for (int m = 0; m < 4; m++)
#pragma unroll
      for (int n = 0; n < 4; n++)
        acc[m][n] = __builtin_amdgcn_mfma_f32_16x16x32_bf16(av[m], bv[n], acc[m][n], 0, 0, 0);
  }
#pragma unroll
  for (int m = 0; m < 4; m++){
#pragma unroll
    for (int r = 0; r < 4; r++){
      int ent = rows[wr*64 + m*16 + g*4 + r];
      if (ent < 0) continue;
#pragma unroll
      for (int n = 0; n < 4; n++){
        int col = n0 + wc*64 + n*16 + r15;
        gu[(size_t)ent*1024 + col] = acc[m][n][r];
      }
    }
  }
}

// ===== MoE GEMM2: act_bf -> down fp32 (x tw), prefetch =====
__global__ __launch_bounds__(256) void moe_gemm2s(
    const ushort* __restrict__ act, const ushort* __restrict__ wdt,
    const int* __restrict__ ecnt, const int* __restrict__ elist,
    const float* __restrict__ tw, float* __restrict__ down){
  int e = blockIdx.z;
  int count = ecnt[e];
  int r0 = blockIdx.y*128;
  if (r0 >= count) return;
  __shared__ int rows[128];
  __shared__ __align__(16) ushort As[5120];
  __shared__ __align__(16) ushort Bs[5120];
  int tid = threadIdx.x, lane = tid & 63, w = tid >> 6;
  int n0 = blockIdx.x*128;
  if (tid < 128) rows[tid] = (r0 + tid < count) ? elist[e*2048 + r0 + tid] : -1;
  __syncthreads();
  int wr = w >> 1, wc = w & 1;
  int r15 = lane & 15, g = lane >> 4;
  int srow = tid >> 1, sh = (tid & 1) << 4;
  int ent0 = rows[srow];
  int src = (ent0 >= 0) ? ent0 : 0;
  const ushort* Ag = act + (size_t)src*512 + sh;
  const ushort* Bg = wdt + ((size_t)e*2048 + n0 + srow)*512 + sh;
  ushort* Asw = &As[srow*40 + sh];
  ushort* Bsw = &Bs[srow*40 + sh];
  int aoff[4], boff[4];
#pragma unroll
  for (int m = 0; m < 4; m++){
    aoff[m] = (wr*64 + m*16 + r15)*40 + g*8;
    boff[m] = (wc*64 + m*16 + r15)*40 + g*8;
  }
  float4v acc[4][4];
#pragma unroll
  for (int i=0;i<4;i++)
#pragma unroll
    for (int j=0;j<4;j++) acc[i][j] = (float4v){0.f,0.f,0.f,0.f};
  short8 a0 = *(const short8*)(Ag);
  short8 a1 = *(const short8*)(Ag + 8);
  short8 b0 = *(const short8*)(Bg);
  short8 b1 = *(const short8*)(Bg + 8);
  for (int kt = 0; kt < 16; kt++){
    __syncthreads();
    *(short8*)Asw = a0; *(short8*)(Asw + 8) = a1;
    *(short8*)Bsw = b0; *(short8*)(Bsw + 8) = b1;
    __syncthreads();
    if (kt < 15){
      int k0 = (kt+1) << 5;
      a0 = *(const short8*)(Ag + k0);
      a1 = *(const short8*)(Ag + k0 + 8);
      b0 = *(const short8*)(Bg + k0);
      b1 = *(const short8*)(Bg + k0 + 8);
    }
    short8 av[4], bv[4];
#pragma unroll
    for (int m = 0; m < 4; m++) av[m] = *(const short8*)&As[aoff[m]];
#pragma unroll
    for (int n = 0; n < 4; n++) bv[n] = *(const short8*)&Bs[boff[n]];
#pragma unroll
    for (int m = 0; m < 4; m++)
#pragma unroll
      for (int n = 0; n < 4; n++)
        acc[m][n] = __builtin_amdgcn_mfma_f32_16x16x32_bf16(av[m], bv[n], acc[m][n], 0, 0, 0);
  }
#pragma unroll
  for (int m = 0; m < 4; m++){
#pragma unroll
    for (int r = 0; r < 4; r++){
      int ent = rows[wr*64 + m*16 + g*4 + r];
      if (ent < 0) continue;
      float wgt = tw[ent];
#pragma unroll
      for (int n = 0; n < 4; n++){
        int col = n0 + wc*64 + n*16 + r15;
        down[(size_t)ent*2048 + col] = acc[m][n][r]*wgt;
      }
    }
  }
}

// ---------------- top-k (stable ties) ----------------
__global__ __launch_bounds__(256) void topk_kernel(
    const float* __restrict__ scores, int* __restrict__ list, int* __restrict__ cnt){
  int t = blockIdx.x, tid = threadIdx.x;
  if (t < ITOPKk){
    for (int i = tid; i <= t; i += 256) list[(size_t)t*ITOPKk + i] = i;
    if (tid==0) cnt[t] = t+1;
    return;
  }
  int n = t+1;
  const float* row = scores + (size_t)t*2048;
  __shared__ unsigned hist[256];
  __shared__ unsigned sh_prefix, sh_krem;
  __shared__ int scan[256];
  __shared__ int sh_base_sel, sh_base_eq;
  if (tid==0){ sh_prefix = 0u; sh_krem = ITOPKk; }
  __syncthreads();
  for (int level = 3; level >= 0; level--){
    int shift = level*8;
    hist[tid] = 0u; __syncthreads();
    unsigned pfx = sh_prefix;
    for (int s = tid; s < n; s += 256){
      unsigned u = mapf(row[s]);
      bool ok = (level==3) || ((u >> (shift+8)) == pfx);
      if (ok) atomicAdd(&hist[(u >> shift) & 255u], 1u);
    }
    __syncthreads();
    if (tid==0){
      unsigned krem = sh_krem, c = 0u; int bsel = 0;
      for (int b = 255; b >= 0; b--){
        if (c + hist[b] >= krem){ bsel = b; break; }
        c += hist[b];
      }
      sh_prefix = (pfx << 8) | (unsigned)bsel;
      sh_krem = krem - c;
    }
    __syncthreads();
  }
  unsigned uth = sh_prefix; int R = (int)sh_krem;
  if (tid==0){ sh_base_sel = 0; sh_base_eq = 0; }
  __syncthreads();
  for (int c0 = 0; c0 < n; c0 += 256){
    int s = c0 + tid;
    unsigned u = (s < n) ? mapf(row[s]) : 0u;
    int gt = (s < n) && (u > uth);
    int eq = (s < n) && (u == uth);
    scan[tid] = (eq << 16) | gt; __syncthreads();
    for (int off = 1; off < 256; off <<= 1){
      int v = (tid >= off) ? scan[tid-off] : 0; __syncthreads();
      scan[tid] += v; __syncthreads();
    }
    int incl = scan[tid];
    int gt_incl = incl & 0xffff, eq_incl = incl >> 16;
    int gt_excl = gt_incl - gt, eq_excl = eq_incl - eq;
    int tot = scan[255]; int gt_tot = tot & 0xffff, eq_tot = tot >> 16;
    int base_sel = sh_base_sel, base_eq = sh_base_eq;
    int rtake = R - base_eq; if (rtake < 0) rtake = 0;
    bool selected = gt || (eq && eq_excl < rtake);
    int pos = base_sel + gt_excl + min(eq_excl, rtake);
    if (selected) list[(size_t)t*ITOPKk + pos] = s;
    __syncthreads();
    if (tid==0){
      sh_base_sel = base_sel + gt_tot + min(eq_tot, rtake);
      sh_base_eq  = base_eq + eq_tot;
    }
    __syncthreads();
  }
  if (tid==0) cnt[t] = ITOPKk;
}

// ---------------- sparse attention (fp32), XCD-aware ----------------------
// QK: 16 lanes per (s,head) dot -> 4-step width-16 shuffle tree. PV: 4 accs.
#define HG 2
__global__ __launch_bounds__(256) void attn_kernel(
    const float* __restrict__ q, const float* __restrict__ kv,
    const float* __restrict__ kpe,
    const int* __restrict__ list, const int* __restrict__ cnt,
    ushort* __restrict__ at_hi, ushort* __restrict__ at_lo){
  int b = blockIdx.x;
  int g8 = b & 7, t = b >> 3;
  int h0 = g8*HG;
  int tid = threadIdx.x, lane = tid & 63, w = tid >> 6;
  __shared__ int   sl[ITOPKk];
  __shared__ float qs[HG][200];
  __shared__ float lg[HG][ITOPKk];
  __shared__ float redm[4], reds[4];
  __shared__ float4 outp4[8][32];
  int n = cnt[t];
  for (int i = tid; i < n; i += 256) sl[i] = list[(size_t)t*ITOPKk + i];
  for (int i = tid; i < HG*192; i += 256){
    int hh = i/192, d = i - hh*192;
    qs[hh][d] = q[(size_t)t*(NHEAD*QKDd) + (h0+hh)*QKDd + d];
  }
  __syncthreads();
  const float scale = 0.07216878364870323f;
  int half = lane >> 5, l4 = lane & 15, grp = (lane >> 4) & 1;
  float4 qv0 = *(const float4*)&qs[half][l4*8];
  float4 qv1 = *(const float4*)&qs[half][l4*8 + 4];
  float4 qp  = *(const float4*)&qs[half][128 + l4*4];
  size_t koff = (size_t)(h0+half)*256 + (size_t)l4*8;
  size_t poff = (size_t)l4*4;
  for (int i0 = w*4; i0 < n; i0 += 16){
    int idx0 = i0 + grp, idx1 = i0 + grp + 2;
    int e0 = (idx0 < n) ? idx0 : n-1;
    int e1 = (idx1 < n) ? idx1 : n-1;
    int s0 = sl[e0], s1 = sl[e1];
    float4 k00 = *(const float4*)(kv + (size_t)s0*4096 + koff);
    float4 k01 = *(const float4*)(kv + (size_t)s0*4096 + koff + 4);
    float4 p0  = *(const float4*)(kpe + (size_t)s0*64 + poff);
    float4 k10 = *(const float4*)(kv + (size_t)s1*4096 + koff);
    float4 k11 = *(const float4*)(kv + (size_t)s1*4096 + koff + 4);
    float4 p1  = *(const float4*)(kpe + (size_t)s1*64 + poff);
    float d0 = k00.x*qv0.x + k00.y*qv0.y + k00.z*qv0.z + k00.w*qv0.w
             + k01.x*qv1.x + k01.y*qv1.y + k01.z*qv1.z + k01.w*qv1.w
             + p0.x*qp.x + p0.y*qp.y + p0.z*qp.z + p0.w*qp.w;
    float d1 = k10.x*qv0.x + k10.y*qv0.y + k10.z*qv0.z + k10.w*qv0.w
             + k11.x*qv1.x + k11.y*qv1.y + k11.z*qv1.z + k11.w*qv1.w
             + p1.x*qp.x + p1.y*qp.y + p1.z*qp.z + p1.w*qp.w;
#pragma unroll
    for (int off = 8; off > 0; off >>= 1){
      d0 += __shfl_down(d0, off, 16);
      d1 += __shfl_down(d1, off, 16);
    }
    if (l4 == 0){
      if (idx0 < n) lg[half][idx0] = d0*scale;
      if (idx1 < n) lg[half][idx1] = d1*scale;
    }
  }
  __syncthreads();
  int slice = tid & 31, sg = tid >> 5;
  for (int hh = 0; hh < HG; hh++){
    int h = h0 + hh;
    float mx = NEGINF;
    for (int i = tid; i < n; i += 256) mx = fmaxf(mx, lg[hh][i]);
    mx = warp_max(mx);
    if (lane==0) redm[w] = mx;
    __syncthreads();
    mx = fmaxf(fmaxf(redm[0],redm[1]), fmaxf(redm[2],redm[3]));
    float sum = 0.f;
    for (int i = tid; i < n; i += 256){ float p = expf(lg[hh][i]-mx); lg[hh][i] = p; sum += p; }
    sum = warp_sum(sum);
    if (lane==0) reds[w] = sum;
    __syncthreads();
    float inv = 1.f/(reds[0]+reds[1]+reds[2]+reds[3]);
    float4 a0 = {0,0,0,0}, a1 = {0,0,0,0}, a2 = {0,0,0,0}, a3 = {0,0,0,0};
    size_t voff = (size_t)h*256 + 128 + slice*4;
    int i = sg;
    for (; i + 24 < n; i += 32){
      float pA = lg[hh][i];
      float4 vA = *(const float4*)(kv + (size_t)sl[i]*4096 + voff);
      float pB = lg[hh][i+8];
      float4 vB = *(const float4*)(kv + (size_t)sl[i+8]*4096 + voff);
      float pC = lg[hh][i+16];
      float4 vC = *(const float4*)(kv + (size_t)sl[i+16]*4096 + voff);
      float pD = lg[hh][i+24];
      float4 vD = *(const float4*)(kv + (size_t)sl[i+24]*4096 + voff);
      a0.x += pA*vA.x; a0.y += pA*vA.y; a0.z += pA*vA.z; a0.w += pA*vA.w;
      a1.x += pB*vB.x; a1.y += pB*vB.y; a1.z += pB*vB.z; a1.w += pB*vB.w;
      a2.x += pC*vC.x; a2.y += pC*vC.y; a2.z += pC*vC.z; a2.w += pC*vC.w;
      a3.x += pD*vD.x; a3.y += pD*vD.y; a3.z += pD*vD.z; a3.w += pD*vD.w;
    }
    for (; i < n; i += 8){
      float p = lg[hh][i];
      float4 v4 = *(const float4*)(kv + (size_t)sl[i]*4096 + voff);
      a0.x += p*v4.x; a0.y += p*v4.y; a0.z += p*v4.z; a0.w += p*v4.w;
    }
    float4 acc;
    acc.x = (a0.x + a1.x) + (a2.x + a3.x);
    acc.y = (a0.y + a1.y) + (a2.y + a3.y);
    acc.z = (a0.z + a1.z) + (a2.z + a3.z);
    acc.w = (a0.w + a1.w) + (a2.w + a3.w);
    outp4[sg][slice] = acc;
    __syncthreads();
    if (tid < 32){
      float4 r = outp4[0][tid];
#pragma unroll
      for (int gg = 1; gg < 8; gg++){
        float4 o = outp4[gg][tid];
        r.x += o.x; r.y += o.y; r.z += o.z; r.w += o.w;
      }
      r.x *= inv; r.y *= inv; r.z *= inv; r.w *= inv;
      size_t o = (size_t)t*2048 + h*128 + tid*4;
      ushort4 hi4, lo4;
      hi4.x = f2bf(r.x); lo4.x = f2bf(r.x - bf2f(hi4.x));
      hi4.y = f2bf(r.y); lo4.y = f2bf(r.y - bf2f(hi4.y));
      hi4.z = f2bf(r.z); lo4.z = f2bf(r.z - bf2f(hi4.z));
      hi4.w = f2bf(r.w); lo4.w = f2bf(r.w - bf2f(hi4.w));
      *(ushort4*)&at_hi[o] = hi4;
      *(ushort4*)&at_lo[o] = lo4;
    }
    __syncthreads();
  }
}

// ---------------- gate ----------------
__global__ void gate_kernel(const float* __restrict__ glog, float* __restrict__ tw,
                            int* __restrict__ ecnt, int* __restrict__ elist){
  int t = blockIdx.x*256 + threadIdx.x;
  if (t >= T_TOK) return;
  float g[8]; float mx = NEGINF;
  for (int i = 0; i < 8; i++){ g[i] = glog[t*8+i]; mx = fmaxf(mx, g[i]); }
  float s = 0.f;
  for (int i = 0; i < 8; i++){ g[i] = expf(g[i]-mx); s += g[i]; }
  for (int i = 0; i < 8; i++) g[i] /= s;
  bool used[8] = {};
  float tv[4]; int si[4];
  for (int k = 0; k < 4; k++){
    float best = -1.f; int bi = 0;
    for (int i = 0; i < 8; i++) if (!used[i] && g[i] > best){ best = g[i]; bi = i; }
    used[bi] = true; tv[k] = best; si[k] = bi;
  }
  float s4 = tv[0]+tv[1]+tv[2]+tv[3];
  for (int k = 0; k < 4; k++){
    tw[t*4+k] = tv[k]/s4;
    int pos = atomicAdd(&ecnt[si[k]], 1);
    elist[si[k]*2048 + pos] = t*4+k;
  }
}

// ---------------- MoE silu: gu [8192,1024] -> act bf16 [8192,512] ----------------
__global__ __launch_bounds__(256) void silu_moe(const float* __restrict__ gu,
                                                ushort* __restrict__ act){
  int i = blockIdx.x*256 + threadIdx.x;
  if (i >= 8192*128) return;
  int row = i >> 7, jc = i & 127;
  float4 g4 = ((const float4*)(gu + (size_t)row*1024))[jc];
  float4 u4 = ((const float4*)(gu + (size_t)row*1024 + 512))[jc];
  ushort4 o;
  o.x = f2bf(g4.x/(1.f+expf(-g4.x))*u4.x);
  o.y = f2bf(g4.y/(1.f+expf(-g4.y))*u4.y);
  o.z = f2bf(g4.z/(1.f+expf(-g4.z))*u4.z);
  o.w = f2bf(g4.w/(1.f+expf(-g4.w))*u4.w);
  ((ushort4*)(act + (size_t)row*512))[jc] = o;
}

// ---------------- combine: out_final += sum of 4 expert slots ----------------
__global__ __launch_bounds__(256) void moe_combine(const float* __restrict__ down,
                                                   float* __restrict__ outf){
  int t = blockIdx.x;
  size_t base = (size_t)t*4*2048;
  for (int d = threadIdx.x; d < 2048; d += 256){
    float s = down[base+d] + down[base+2048+d] + down[base+4096+d] + down[base+6144+d];
    outf[(size_t)t*2048 + d] += s;
  }
}

// ---------------- shared-expert silu -> bf16 ----------------
__global__ __launch_bounds__(256) void silu_sh(const float* __restrict__ sgu,
                                               ushort* __restrict__ shact){
  int i = blockIdx.x*256 + threadIdx.x;
  if (i >= 2048*256) return;
  int row = i >> 8, jc = i & 255;
  float4 g4 = ((const float4*)(sgu + (size_t)row*2048))[jc];
  float4 u4 = ((const float4*)(sgu + (size_t)row*2048 + 1024))[jc];
  ushort4 o;
  o.x = f2bf(g4.x/(1.f+expf(-g4.x))*u4.x);
  o.y = f2bf(g4.y/(1.f+expf(-g4.y))*u4.y);
  o.z = f2bf(g4.z/(1.f+expf(-g4.z))*u4.z);
  o.w = f2bf(g4.w/(1.f+expf(-g4.w))*u4.w);
  ((ushort4*)(shact + (size_t)row*1024))[jc] = o;
}

// ---------------- host ----------------
extern "C" void kernel_launch(void* const* d_in, const int* in_sizes, int n_in,
                              void* d_out, int out_size, void* d_ws, size_t ws_size,
                              hipStream_t stream){
  const int*   positions  = (const int*)  d_in[0];
  const float* hidden     = (const float*)d_in[1];
  const float* ln1_w      = (const float*)d_in[2];
  const float* ln2_w      = (const float*)d_in[3];
  const float* w_qkv_a    = (const float*)d_in[4];
  const float* q_a_ln_w   = (const float*)d_in[5];
  const float* kv_a_ln_w  = (const float*)d_in[6];
  const float* w_q_b      = (const float*)d_in[7];
  const float* w_kv_b     = (const float*)d_in[8];
  const float* w_o        = (const float*)d_in[9];
  const float* w_idx_k    = (const float*)d_in[10];
  const float* idx_k_ln_w = (const float*)d_in[11];
  const float* idx_k_ln_b = (const float*)d_in[12];
  const float* w_idx_qb   = (const float*)d_in[13];
  const float* w_idx_w    = (const float*)d_in[14];
  const float* w_gate     = (const float*)d_in[15];
  const float* w_moe_gu   = (const float*)d_in[16];
  const float* w_moe_d    = (const float*)d_in[17];
  const float* w_sh_gu    = (const float*)d_in[18];
  const float* w_sh_d     = (const float*)d_in[19];

  float* out_final = (float*)d_out;                       // [T,2048]
  float* residual  = (float*)d_out + (size_t)T_TOK*HIDN;  // [T,2048]

  float* ws = (float*)d_ws;
  // ---- arena (19,005,440 floats) with phase overlays ----
  float* arena   = ws;
  float* qkv_main= arena;                  // [T,2048]  phase1
  float* qkv_pe  = arena + 4194304;        // [T,64]
  float* iscores = arena;                  // [T,T]     overlays qkv (dead)
  float* qbuf    = arena + 4325376;        // [T,16,192]
  float* idx_q   = arena + 10616832;       // [T,16,128] fp32 (pre-rope)
  float* sgu     = arena;                  // phase2 overlays
  float* gu_buf  = arena;
  float* down_buf= arena;
  ushort* act_bf = (ushort*)(arena + 16777216); // [8192,512] bf16
  // qkv_a/idx_k-step split scratch:
  ushort* h_hi  = (ushort*)(arena + 4325376);   // 4,194,304 ush
  ushort* h_lo  = h_hi + 4194304;
  ushort* wqa_hi= (ushort*)(arena + 8519680);   // 4,325,376 ush
  ushort* wqa_lo= wqa_hi + 4325376;
  ushort* wik_hi= (ushort*)(arena + 12845056);  // 262,144 ush
  ushort* wik_lo= wik_hi + 262144;
  // idx_qb-step weight scratch (clobbers h splits after idx_k gemm):
  ushort* wiq_hi= (ushort*)(arena + 4325376);   // 3,145,728 ush
  ushort* wiq_lo= wiq_hi + 3145728;
  // indexer split buffers:
  ushort* ik_hi = (ushort*)(arena + 4325376);   // 262,144 ush (after idx_qb; wiq dead)
  ushort* ik_lo = ik_hi + 262144;
  ushort* iq_hi = (ushort*)(arena + 14811136);  // 4,194,304 ush
  ushort* iq_lo = iq_hi + 4194304;
  // post-topk scratch:
  ushort* s1 = (ushort*)arena;                  // iscores region
  ushort* s2 = (ushort*)(arena + 10616832);     // idx_q/iq region
  // ---- fixed fp32 tail ----
  size_t off = 19005440;
  float* h      = ws + off; off += 4194304;   // [T,2048]
  float* kv     = ws + off; off += 8388608;   // [T,16,256] fp32 (qc-split overlay first)
  float* attnbuf= ws + off; off += 4194304;   // kvc-split overlay / wmd_t
  float* k_pe   = ws + off; off += 131072;
  float* idx_k  = ws + off; off += 262144;    // [T,128] fp32 (pre-LN)
  float* idx_w  = ws + off; off += 32768;
  float* glog   = ws + off; off += 16384;
  float* tw     = ws + off; off += 8192;
  float* ctab   = ws + off; off += 65536;
  float* stab   = ws + off; off += 65536;
  int* list     = (int*)(ws + off);           // [T,512]
  int* cnt      = list + 1048576;
  int* ecnt     = cnt + 2048;
  int* elist    = ecnt + 8;
  off += 1067016;
  // ---- ushort region ----
  ushort* h2_bf   = (ushort*)(ws + off); off += 2097152;
  ushort* shact_bf= (ushort*)(ws + off); off += 1048576;
  ushort* wshgu_t = (ushort*)(ws + off); off += 2097152;
  ushort* wshd_t  = (ushort*)(ws + off); off += 1048576;   // total 43,722,760 floats
  // overlays on dead tail fp32 buffers:
  ushort* qc_hi  = (ushort*)kv;               // dead until kv_b
  ushort* qc_lo  = qc_hi + 3145728;
  ushort* kvc_hi = (ushort*)attnbuf;          // dead until MoE transposes
  ushort* kvc_lo = kvc_hi + 1048576;
  ushort* wmgu_t = (ushort*)kv;
  ushort* wmd_t  = (ushort*)attnbuf;
  size_t total_bytes = off * sizeof(float);
  if (ws_size < total_bytes) return;

  // post-topk scratch assignments:
  ushort* wqbt_hi= s2;
  ushort* wqbt_lo= s2 + 4718592;
  ushort* wkvt_hi= s1;
  ushort* wkvt_lo= s1 + 2097152;
  ushort* at_hi  = s2;                 // attn writes split output here
  ushort* at_lo  = s2 + 4194304;
  ushort* wot_hi = s1;
  ushort* wot_lo = s1 + 4194304;

  // shared-expert weight transposes (consumed after gate)
  transconv<<<dim3(64,64,1), 256, 0, stream>>>(w_sh_gu, wshgu_t, 2048, 2048);
  transconv<<<dim3(64,32,1), 256, 0, stream>>>(w_sh_d,  wshd_t,  1024, 2048);

  rope_table_kernel<<<T_TOK, 32, 0, stream>>>(positions, ctab, stab);
  rmsnorm_kernel<<<T_TOK, 256, 0, stream>>>(hidden, HIDN, 0, ln1_w, h, HIDN, HIDN);
  // ---- qkv_a via split-bf16 MFMA (2048 cols) + fp32 (pe 64 cols) ----
  split_bf16<<<4096, 256, 0, stream>>>(h, h_hi, h_lo, 1048576);
  transconv_split<<<dim3(66,64), 256, 0, stream>>>(w_qkv_a, wqa_hi, wqa_lo, 2048, 2112);
  gemm_b3<<<dim3(16,16), 256, 0, stream>>>(h_hi, h_lo, wqa_hi, wqa_lo, qkv_main, nullptr, 2048, 2048);
  gemm_f32<<<dim3(1,32), 256, 0, stream>>>(h, HIDN, w_qkv_a + 2048, 2112, qkv_pe, 64, nullptr, 0, T_TOK, 64, HIDN, 1.f);
  // ---- fused rmsnorm -> split for q_c / kv_c ----
  rmsnorm_split<<<T_TOK, 256, 0, stream>>>(qkv_main, 2048, 0,    q_a_ln_w,  qc_hi,  qc_lo,  QLRr,  QLRr);
  rmsnorm_split<<<T_TOK, 256, 0, stream>>>(qkv_main, 2048, QLRr, kv_a_ln_w, kvc_hi, kvc_lo, KVLRr, KVLRr);
  rope_kpe_kernel<<<T_TOK, 32, 0, stream>>>(qkv_pe, ctab, stab, k_pe);
  // ---- idx_k via split-bf16 MFMA (fp32 pre-LN out) ----
  transconv_split<<<dim3(4,64), 256, 0, stream>>>(w_idx_k, wik_hi, wik_lo, 2048, 128);
  gemm_b3<<<dim3(1,16), 256, 0, stream>>>(h_hi, h_lo, wik_hi, wik_lo, idx_k, nullptr, 128, 2048);
  // ---- idx_qb via split-bf16 MFMA ----
  transconv_split<<<dim3(64,48), 256, 0, stream>>>(w_idx_qb, wiq_hi, wiq_lo, 1536, 2048);
  gemm_b3<<<dim3(16,16), 256, 0, stream>>>(qc_hi, qc_lo, wiq_hi, wiq_lo, idx_q, nullptr, 2048, 1536);
  // ---- fused rope -> split for idx_q ----
  rope_idxq_split<<<T_TOK, 256, 0, stream>>>(idx_q, ctab, stab, iq_hi, iq_lo);
  // ---- fused LN+rope -> split for idx_k (wiq dead now) ----
  ln_rope_idxk_split<<<T_TOK, 128, 0, stream>>>(idx_k, idx_k_ln_w, idx_k_ln_b, ctab, stab, ik_hi, ik_lo);
  // ---- idx_w (tiny fp32) ----
  gemm_f32<<<dim3(1,32), 256, 0, stream>>>(h, HIDN, w_idx_w, INHh, idx_w, INHh, nullptr, 0, T_TOK, INHh, HIDN, 0.02209708691207961f);
  // ---- iscores via split-bf16 MFMA (triangular) ----
  iscores_b3<<<dim3(16,16), 256, 0, stream>>>(iq_hi, iq_lo, ik_hi, ik_lo, idx_w, iscores);
  topk_kernel<<<T_TOK, 256, 0, stream>>>(iscores, list, cnt);
  // ---- q_b via split-bf16 MFMA ----
  transconv_split<<<dim3(96,48), 256, 0, stream>>>(w_q_b, wqbt_hi, wqbt_lo, 1536, 3072);
  gemm_b3<<<dim3(24,16), 256, 0, stream>>>(qc_hi, qc_lo, wqbt_hi, wqbt_lo, qbuf, nullptr, 3072, 1536);
  rope_q_kernel<<<T_TOK, 256, 0, stream>>>(qbuf, ctab, stab);
  // ---- kv_b via split-bf16 MFMA (qc splits dead -> kv fp32 reuse OK) ----
  transconv_split<<<dim3(128,16), 256, 0, stream>>>(w_kv_b, wkvt_hi, wkvt_lo, 512, 4096);
  gemm_b3<<<dim3(32,16), 256, 0, stream>>>(kvc_hi, kvc_lo, wkvt_hi, wkvt_lo, kv, nullptr, 4096, 512);
  // ---- attention (writes split hi/lo output directly) ----
  attn_kernel<<<T_TOK*(NHEAD/HG), 256, 0, stream>>>(qbuf, kv, k_pe, list, cnt, at_hi, at_lo);
  // ---- w_o via split-bf16 MFMA (+hidden -> residual) ----
  transconv_split<<<dim3(64,64), 256, 0, stream>>>(w_o, wot_hi, wot_lo, 2048, 2048);
  gemm_b3<<<dim3(16,16), 256, 0, stream>>>(at_hi, at_lo, wot_hi, wot_lo, residual, hidden, 2048, 2048);
  // kv/attnbuf now dead -> MoE weight transposes into their space
  transconv<<<dim3(32,64,8), 256, 0, stream>>>(w_moe_gu, wmgu_t, 2048, 1024);
  transconv<<<dim3(64,16,8), 256, 0, stream>>>(w_moe_d,  wmd_t,  512,  2048);
  rmsnorm_kernel<<<T_TOK, 256, 0, stream>>>(residual, HIDN, 0, ln2_w, h, HIDN, HIDN);
  gemm_f32<<<dim3(1,32), 256, 0, stream>>>(h, HIDN, w_gate, NEXP, glog, NEXP, nullptr, 0, T_TOK, NEXP, HIDN, 1.f);
  hipMemsetAsync(ecnt, 0, NEXP*sizeof(int), stream);
  gate_kernel<<<8, 256, 0, stream>>>(glog, tw, ecnt, elist);
  conv_bf16<<<4096, 256, 0, stream>>>(h, h2_bf, 1048576);
  // shared expert (arena as sgu)
  gemm_bf16s<0><<<dim3(16,16), 256, 0, stream>>>(h2_bf, wshgu_t, sgu, nullptr, nullptr, 2048, 2048);
  silu_sh<<<2048, 256, 0, stream>>>(sgu, shact_bf);
  gemm_bf16s<0><<<dim3(16,16), 256, 0, stream>>>(shact_bf, wshd_t, out_final, nullptr, nullptr, 2048, 1024);
  // MoE (arena as gu -> act_bf -> down)
  moe_gemm1s<<<dim3(8, 16, NEXP), 256, 0, stream>>>(h2_bf, wmgu_t, ecnt, elist, gu_buf);
  silu_moe<<<4096, 256, 0, stream>>>(gu_buf, act_bf);
  moe_gemm2s<<<dim3(16, 16, NEXP), 256, 0, stream>>>(act_bf, wmd_t, ecnt, elist, tw, down_buf);
  moe_combine<<<T_TOK, 256, 0, stream>>>(down_buf, out_final);
  (void)in_sizes; (void)n_in; (void)out_size;
}

// Round 20
// 2325.934 us; speedup vs baseline: 1.0317x; 1.0317x over previous
//
#include <hip/hip_runtime.h>
#include <cstdint>
#include <cstddef>

#define T_TOK 2048
#define HIDN  2048
#define NHEAD 16
#define QLRr  1536
#define KVLRr 512
#define DNn   128
#define DRr   64
#define DVv   128
#define QKDd  192
#define INHh  16
#define IHDd  128
#define ITOPKk 512
#define NEXP  8
#define MIi   512
#define SHMI  1024
#define EPSF  1e-6f
#define NEGINF (-3.402823466e38f)

typedef __attribute__((ext_vector_type(8))) short short8;
typedef __attribute__((ext_vector_type(4))) float float4v;

// ---------------- helpers ----------------
__device__ __forceinline__ float warp_sum(float v){
#pragma unroll
  for (int off=32; off>0; off>>=1) v += __shfl_down(v, off, 64);
  return v;
}
__device__ __forceinline__ float warp_max(float v){
#pragma unroll
  for (int off=32; off>0; off>>=1) v = fmaxf(v, __shfl_down(v, off, 64));
  return v;
}
__device__ __forceinline__ unsigned mapf(float f){
  unsigned b = __float_as_uint(f);
  if ((b<<1)==0u) b = 0u;
  return (b & 0x80000000u) ? ~b : (b | 0x80000000u);
}
__device__ __forceinline__ ushort f2bf(float f){
  unsigned u = __float_as_uint(f);
  unsigned r = (u + 0x7fffu + ((u>>16)&1u)) >> 16;
  return (ushort)r;
}
__device__ __forceinline__ float bf2f(ushort u){
  return __uint_as_float(((unsigned)u) << 16);
}

// ---------------- rope tables ----------------
__global__ void rope_table_kernel(const int* __restrict__ pos,
                                  float* __restrict__ ct, float* __restrict__ st){
  int t = blockIdx.x, j = threadIdx.x;          // blockDim 32
  float inv = powf(10000.0f, -(float)j * (1.0f/32.0f));
  float f = (float)pos[t] * inv;
  ct[t*32+j] = cosf(f);
  st[t*32+j] = sinf(f);
}

// ---------------- rmsnorm (fp32 out) ----------------
__global__ __launch_bounds__(256) void rmsnorm_kernel(
    const float* __restrict__ x, int xstride, int xoff,
    const float* __restrict__ w, float* __restrict__ out, int ostride, int D){
  int t = blockIdx.x, tid = threadIdx.x;
  const float* xp = x + (size_t)t*xstride + xoff;
  const float4* x4 = (const float4*)xp;
  int D4 = D >> 2;
  float ss = 0.f;
  for (int i = tid; i < D4; i += 256){ float4 v = x4[i]; ss += v.x*v.x+v.y*v.y+v.z*v.z+v.w*v.w; }
  __shared__ float red[4];
  float s = warp_sum(ss);
  int lane = tid & 63, wid = tid >> 6;
  if (lane==0) red[wid] = s;
  __syncthreads();
  if (tid==0) red[0] = red[0]+red[1]+red[2]+red[3];
  __syncthreads();
  float sc = rsqrtf(red[0]/(float)D + EPSF);
  const float4* w4 = (const float4*)w;
  float4* o4 = (float4*)(out + (size_t)t*ostride);
  for (int i = tid; i < D4; i += 256){
    float4 v = x4[i], ww = w4[i];
    float4 r; r.x=v.x*sc*ww.x; r.y=v.y*sc*ww.y; r.z=v.z*sc*ww.z; r.w=v.w*sc*ww.w;
    o4[i] = r;
  }
}

// ---------------- rmsnorm emitting fp32 AND split hi/lo (fused) ------------
__global__ __launch_bounds__(256) void rmsnorm_both(
    const float* __restrict__ x, int xstride, int xoff,
    const float* __restrict__ w, float* __restrict__ out,
    ushort* __restrict__ hi, ushort* __restrict__ lo,
    int ostride, int D){
  int t = blockIdx.x, tid = threadIdx.x;
  const float* xp = x + (size_t)t*xstride + xoff;
  const float4* x4 = (const float4*)xp;
  int D4 = D >> 2;
  float ss = 0.f;
  for (int i = tid; i < D4; i += 256){ float4 v = x4[i]; ss += v.x*v.x+v.y*v.y+v.z*v.z+v.w*v.w; }
  __shared__ float red[4];
  float s = warp_sum(ss);
  int lane = tid & 63, wid = tid >> 6;
  if (lane==0) red[wid] = s;
  __syncthreads();
  if (tid==0) red[0] = red[0]+red[1]+red[2]+red[3];
  __syncthreads();
  float sc = rsqrtf(red[0]/(float)D + EPSF);
  const float4* w4 = (const float4*)w;
  float4* o4 = (float4*)(out + (size_t)t*ostride);
  ushort4* h4 = (ushort4*)(hi + (size_t)t*ostride);
  ushort4* l4 = (ushort4*)(lo + (size_t)t*ostride);
  for (int i = tid; i < D4; i += 256){
    float4 v = x4[i], ww = w4[i];
    float4 r; r.x=v.x*sc*ww.x; r.y=v.y*sc*ww.y; r.z=v.z*sc*ww.z; r.w=v.w*sc*ww.w;
    o4[i] = r;
    ushort4 hh, ll;
    hh.x = f2bf(r.x); ll.x = f2bf(r.x - bf2f(hh.x));
    hh.y = f2bf(r.y); ll.y = f2bf(r.y - bf2f(hh.y));
    hh.z = f2bf(r.z); ll.z = f2bf(r.z - bf2f(hh.z));
    hh.w = f2bf(r.w); ll.w = f2bf(r.w - bf2f(hh.w));
    h4[i] = hh; l4[i] = ll;
  }
}

// ---------------- rmsnorm emitting fp32 AND bf16 (fused) ----------------
__global__ __launch_bounds__(256) void rmsnorm_bfo(
    const float* __restrict__ x, int xstride, int xoff,
    const float* __restrict__ w, float* __restrict__ out,
    ushort* __restrict__ bfo, int ostride, int D){
  int t = blockIdx.x, tid = threadIdx.x;
  const float* xp = x + (size_t)t*xstride + xoff;
  const float4* x4 = (const float4*)xp;
  int D4 = D >> 2;
  float ss = 0.f;
  for (int i = tid; i < D4; i += 256){ float4 v = x4[i]; ss += v.x*v.x+v.y*v.y+v.z*v.z+v.w*v.w; }
  __shared__ float red[4];
  float s = warp_sum(ss);
  int lane = tid & 63, wid = tid >> 6;
  if (lane==0) red[wid] = s;
  __syncthreads();
  if (tid==0) red[0] = red[0]+red[1]+red[2]+red[3];
  __syncthreads();
  float sc = rsqrtf(red[0]/(float)D + EPSF);
  const float4* w4 = (const float4*)w;
  float4* o4 = (float4*)(out + (size_t)t*ostride);
  ushort4* b4 = (ushort4*)(bfo + (size_t)t*ostride);
  for (int i = tid; i < D4; i += 256){
    float4 v = x4[i], ww = w4[i];
    float4 r; r.x=v.x*sc*ww.x; r.y=v.y*sc*ww.y; r.z=v.z*sc*ww.z; r.w=v.w*sc*ww.w;
    o4[i] = r;
    ushort4 o; o.x=f2bf(r.x); o.y=f2bf(r.y); o.z=f2bf(r.z); o.w=f2bf(r.w);
    b4[i] = o;
  }
}

// ---------------- rmsnorm emitting split hi/lo bf16 directly ----------------
__global__ __launch_bounds__(256) void rmsnorm_split(
    const float* __restrict__ x, int xstride, int xoff,
    const float* __restrict__ w, ushort* __restrict__ hi, ushort* __restrict__ lo,
    int ostride, int D){
  int t = blockIdx.x, tid = threadIdx.x;
  const float* xp = x + (size_t)t*xstride + xoff;
  const float4* x4 = (const float4*)xp;
  int D4 = D >> 2;
  float ss = 0.f;
  for (int i = tid; i < D4; i += 256){ float4 v = x4[i]; ss += v.x*v.x+v.y*v.y+v.z*v.z+v.w*v.w; }
  __shared__ float red[4];
  float s = warp_sum(ss);
  int lane = tid & 63, wid = tid >> 6;
  if (lane==0) red[wid] = s;
  __syncthreads();
  if (tid==0) red[0] = red[0]+red[1]+red[2]+red[3];
  __syncthreads();
  float sc = rsqrtf(red[0]/(float)D + EPSF);
  const float4* w4 = (const float4*)w;
  ushort4* h4 = (ushort4*)(hi + (size_t)t*ostride);
  ushort4* l4 = (ushort4*)(lo + (size_t)t*ostride);
  for (int i = tid; i < D4; i += 256){
    float4 v = x4[i], ww = w4[i];
    float4 r; r.x=v.x*sc*ww.x; r.y=v.y*sc*ww.y; r.z=v.z*sc*ww.z; r.w=v.w*sc*ww.w;
    ushort4 hh, ll;
    hh.x = f2bf(r.x); ll.x = f2bf(r.x - bf2f(hh.x));
    hh.y = f2bf(r.y); ll.y = f2bf(r.y - bf2f(hh.y));
    hh.z = f2bf(r.z); ll.z = f2bf(r.z - bf2f(hh.z));
    hh.w = f2bf(r.w); ll.w = f2bf(r.w - bf2f(hh.w));
    h4[i] = hh; l4[i] = ll;
  }
}

// ---------------- k_pe rope (fp32 out) ----------------
__global__ void rope_kpe_kernel(const float* __restrict__ pe,
                                const float* __restrict__ ct, const float* __restrict__ st,
                                float* __restrict__ kpe){
  int t = blockIdx.x, j = threadIdx.x;          // blockDim 32
  const float* x = pe + (size_t)t*64;
  float x1 = x[j], x2 = x[32+j];
  float c = ct[t*32+j], sn = st[t*32+j];
  kpe[t*64+j]    = x1*c - x2*sn;
  kpe[t*64+32+j] = x1*sn + x2*c;
}

// ---------------- idx_k layernorm + rope, emitting split hi/lo ------------
__global__ __launch_bounds__(128) void ln_rope_idxk_split(
    const float* __restrict__ xk, const float* __restrict__ w, const float* __restrict__ b,
    const float* __restrict__ ct, const float* __restrict__ st,
    ushort* __restrict__ hi, ushort* __restrict__ lo){
  int t = blockIdx.x, tid = threadIdx.x;
  float v = xk[(size_t)t*IHDd + tid];
  float s1 = warp_sum(v), s2 = warp_sum(v*v);
  __shared__ float r1[2], r2[2];
  int lane = tid & 63, wid = tid >> 6;
  if (lane==0){ r1[wid]=s1; r2[wid]=s2; }
  __syncthreads();
  float mean = (r1[0]+r1[1]) * (1.f/128.f);
  float var  = (r2[0]+r2[1]) * (1.f/128.f) - mean*mean;
  float y = (v-mean)*rsqrtf(var+EPSF)*w[tid]+b[tid];
  __shared__ float ly[128];
  ly[tid] = y; __syncthreads();
  float o;
  if (tid < 64) o = y;
  else if (tid < 96){ int j = tid-64; o = ly[64+j]*ct[t*32+j] - ly[96+j]*st[t*32+j]; }
  else              { int j = tid-96; o = ly[64+j]*st[t*32+j] + ly[96+j]*ct[t*32+j]; }
  ushort hh = f2bf(o);
  hi[(size_t)t*IHDd + tid] = hh;
  lo[(size_t)t*IHDd + tid] = f2bf(o - bf2f(hh));
}

// ---------------- rope over q ----------------
__global__ __launch_bounds__(256) void rope_q_kernel(float* __restrict__ q,
                                  const float* __restrict__ ct, const float* __restrict__ st){
  int t = blockIdx.x, tid = threadIdx.x;
  __shared__ float c[32], s[32];
  if (tid < 32){ c[tid]=ct[t*32+tid]; s[tid]=st[t*32+tid]; }
  __syncthreads();
  for (int idx = tid; idx < NHEAD*32; idx += 256){
    int hh = idx >> 5, j = idx & 31;
    float* base = q + (size_t)t*(NHEAD*QKDd) + hh*QKDd;
    float x1 = base[DNn+j], x2 = base[DNn+32+j];
    base[DNn+j]    = x1*c[j] - x2*s[j];
    base[DNn+32+j] = x1*s[j] + x2*c[j];
  }
}

// ---------------- rope over idx_q, emitting split hi/lo ----------------
__global__ __launch_bounds__(256) void rope_idxq_split(const float* __restrict__ q,
                                  const float* __restrict__ ct, const float* __restrict__ st,
                                  ushort* __restrict__ hi, ushort* __restrict__ lo){
  int t = blockIdx.x, tid = threadIdx.x;
  __shared__ float c[32], s[32];
  if (tid < 32){ c[tid]=ct[t*32+tid]; s[tid]=st[t*32+tid]; }
  __syncthreads();
  const float* row = q + (size_t)t*2048;
  for (int idx = tid; idx < 2048; idx += 256){
    int d = idx & 127; int base = idx - d;
    float v;
    if (d < 64) v = row[idx];
    else if (d < 96){ int j = d-64; v = row[base+64+j]*c[j] - row[base+96+j]*s[j]; }
    else            { int j = d-96; v = row[base+64+j]*s[j] + row[base+96+j]*c[j]; }
    ushort hh = f2bf(v);
    hi[(size_t)t*2048 + idx] = hh;
    lo[(size_t)t*2048 + idx] = f2bf(v - bf2f(hh));
  }
}

// ---------------- fp32 GEMM, 64x64 tile (small N only) ----------------
__global__ __launch_bounds__(256) void gemm_f32(
    const float* __restrict__ A, int lda,
    const float* __restrict__ B, int ldb,
    float* __restrict__ C, int ldc,
    const float* __restrict__ addsrc, int ldadd,
    int M, int N, int K, float alpha){
  __shared__ float As[16][68];
  __shared__ float Bs[16][68];
  int tid = threadIdx.x;
  int tx = tid & 15, ty = tid >> 4;
  int m0 = blockIdx.y*64, n0 = blockIdx.x*64;
  float acc[4][4] = {};
  for (int k0 = 0; k0 < K; k0 += 16){
#pragma unroll
    for (int i = 0; i < 4; i++){
      int lin = tid + i*256; int r = lin >> 4, c = lin & 15;
      int m = m0 + r;
      As[c][r] = (m < M) ? A[(size_t)m*lda + k0 + c] : 0.f;
    }
#pragma unroll
    for (int i = 0; i < 4; i++){
      int lin = tid + i*256; int kk = lin >> 6, c = lin & 63;
      int n = n0 + c;
      Bs[kk][c] = (n < N) ? B[(size_t)(k0+kk)*ldb + n] : 0.f;
    }
    __syncthreads();
#pragma unroll
    for (int kk = 0; kk < 16; kk++){
      float4 av = *(const float4*)&As[kk][ty*4];
      float4 bv = *(const float4*)&Bs[kk][tx*4];
      float a[4] = {av.x, av.y, av.z, av.w};
      float b[4] = {bv.x, bv.y, bv.z, bv.w};
#pragma unroll
      for (int i = 0; i < 4; i++)
#pragma unroll
        for (int j = 0; j < 4; j++) acc[i][j] += a[i]*b[j];
    }
    __syncthreads();
  }
#pragma unroll
  for (int i = 0; i < 4; i++){
    int m = m0 + ty*4 + i;
    if (m >= M) continue;
#pragma unroll
    for (int j = 0; j < 4; j++){
      int n = n0 + tx*4 + j;
      if (n >= N) continue;
      float v = acc[i][j]*alpha;
      if (addsrc) v += addsrc[(size_t)m*ldadd + n];
      C[(size_t)m*ldc + n] = v;
    }
  }
}

// ---------------- split fp32 -> (hi, lo) bf16 pair ----------------
__global__ __launch_bounds__(256) void split_bf16(const float* __restrict__ in,
                                                  ushort* __restrict__ hi,
                                                  ushort* __restrict__ lo, int n4){
  int i = blockIdx.x*256 + threadIdx.x;
  if (i >= n4) return;
  float4 v = ((const float4*)in)[i];
  ushort4 h, l;
  h.x = f2bf(v.x); l.x = f2bf(v.x - bf2f(h.x));
  h.y = f2bf(v.y); l.y = f2bf(v.y - bf2f(h.y));
  h.z = f2bf(v.z); l.z = f2bf(v.z - bf2f(h.z));
  h.w = f2bf(v.w); l.w = f2bf(v.w - bf2f(h.w));
  ((ushort4*)hi)[i] = h;
  ((ushort4*)lo)[i] = l;
}

// ---------------- transpose + convert: src[K,N] fp32 -> dst[N,K] bf16 ----------------
__global__ __launch_bounds__(256) void transconv(const float* __restrict__ src0,
                                                 ushort* __restrict__ dst0, int K, int N){
  int e = blockIdx.z;
  const float* src = src0 + (size_t)e*K*N;
  ushort* dst = dst0 + (size_t)e*N*K;
  int k0 = blockIdx.y*32, n0 = blockIdx.x*32;
  __shared__ float tile[32][33];
  int c = threadIdx.x & 31, r = threadIdx.x >> 5;
  for (int rr = r; rr < 32; rr += 8) tile[rr][c] = src[(size_t)(k0+rr)*N + n0 + c];
  __syncthreads();
  for (int rr = r; rr < 32; rr += 8) dst[(size_t)(n0+rr)*K + k0 + c] = f2bf(tile[c][rr]);
}

// ---------------- transpose + split: src[K,N] fp32 -> hi/lo [N,K] bf16 ----------------
__global__ __launch_bounds__(256) void transconv_split(const float* __restrict__ src,
                                                       ushort* __restrict__ dhi,
                                                       ushort* __restrict__ dlo, int K, int N){
  int k0 = blockIdx.y*32, n0 = blockIdx.x*32;
  __shared__ float tile[32][33];
  int c = threadIdx.x & 31, r = threadIdx.x >> 5;
  for (int rr = r; rr < 32; rr += 8) tile[rr][c] = src[(size_t)(k0+rr)*N + n0 + c];
  __syncthreads();
  for (int rr = r; rr < 32; rr += 8){
    float x = tile[c][rr];
    ushort h = f2bf(x);
    ushort l = f2bf(x - bf2f(h));
    size_t o = (size_t)(n0+rr)*K + k0 + c;
    dhi[o] = h; dlo[o] = l;
  }
}

// ===== split-bf16 (Markidis) MFMA GEMM with register prefetch =====
// loop: sync -> write LDS(kt) -> sync -> issue loads(kt+1) -> frags+MFMA(kt)
__global__ __launch_bounds__(256) void gemm_b3(
    const ushort* __restrict__ Ah, const ushort* __restrict__ Al,
    const ushort* __restrict__ Bh, const ushort* __restrict__ Bl,
    float* __restrict__ C, const float* __restrict__ addsrc, int N, int K){
  __shared__ __align__(16) ushort Ahs[5120], Als[5120];
  __shared__ __align__(16) ushort Bhs[5120], Bls[5120];
  int tid = threadIdx.x, lane = tid & 63, w = tid >> 6;
  int m0 = blockIdx.y*128, n0 = blockIdx.x*128;
  int wr = w >> 1, wc = w & 1;
  int r15 = lane & 15, g = lane >> 4;
  int srow = tid >> 1, sh = (tid & 1) << 4;
  size_t arow = (size_t)(m0 + srow)*K + sh;
  size_t brow = (size_t)(n0 + srow)*K + sh;
  int soff = srow*40 + sh;
  int aoff[4], boff[4];
#pragma unroll
  for (int m = 0; m < 4; m++){
    aoff[m] = (wr*64 + m*16 + r15)*40 + g*8;
    boff[m] = (wc*64 + m*16 + r15)*40 + g*8;
  }
  float4v acc[4][4];
#pragma unroll
  for (int i=0;i<4;i++)
#pragma unroll
    for (int j=0;j<4;j++) acc[i][j] = (float4v){0.f,0.f,0.f,0.f};
  int nk = K >> 5;
  short8 ah0 = *(const short8*)(Ah + arow);
  short8 ah1 = *(const short8*)(Ah + arow + 8);
  short8 al0 = *(const short8*)(Al + arow);
  short8 al1 = *(const short8*)(Al + arow + 8);
  short8 bh0 = *(const short8*)(Bh + brow);
  short8 bh1 = *(const short8*)(Bh + brow + 8);
  short8 bl0 = *(const short8*)(Bl + brow);
  short8 bl1 = *(const short8*)(Bl + brow + 8);
  for (int kt = 0; kt < nk; kt++){
    __syncthreads();
    *(short8*)&Ahs[soff] = ah0; *(short8*)&Ahs[soff+8] = ah1;
    *(short8*)&Als[soff] = al0; *(short8*)&Als[soff+8] = al1;
    *(short8*)&Bhs[soff] = bh0; *(short8*)&Bhs[soff+8] = bh1;
    *(short8*)&Bls[soff] = bl0; *(short8*)&Bls[soff+8] = bl1;
    __syncthreads();
    if (kt+1 < nk){
      int k0 = (kt+1) << 5;
      ah0 = *(const short8*)(Ah + arow + k0);
      ah1 = *(const short8*)(Ah + arow + k0 + 8);
      al0 = *(const short8*)(Al + arow + k0);
      al1 = *(const short8*)(Al + arow + k0 + 8);
      bh0 = *(const short8*)(Bh + brow + k0);
      bh1 = *(const short8*)(Bh + brow + k0 + 8);
      bl0 = *(const short8*)(Bl + brow + k0);
      bl1 = *(const short8*)(Bl + brow + k0 + 8);
    }
    short8 avh[4], avl[4], bvh[4], bvl[4];
#pragma unroll
    for (int m = 0; m < 4; m++){
      avh[m] = *(const short8*)&Ahs[aoff[m]];
      avl[m] = *(const short8*)&Als[aoff[m]];
    }
#pragma unroll
    for (int n = 0; n < 4; n++){
      bvh[n] = *(const short8*)&Bhs[boff[n]];
      bvl[n] = *(const short8*)&Bls[boff[n]];
    }
#pragma unroll
    for (int m = 0; m < 4; m++)
#pragma unroll
      for (int n = 0; n < 4; n++){
        acc[m][n] = __builtin_amdgcn_mfma_f32_16x16x32_bf16(avh[m], bvh[n], acc[m][n], 0, 0, 0);
        acc[m][n] = __builtin_amdgcn_mfma_f32_16x16x32_bf16(avl[m], bvh[n], acc[m][n], 0, 0, 0);
        acc[m][n] = __builtin_amdgcn_mfma_f32_16x16x32_bf16(avh[m], bvl[n], acc[m][n], 0, 0, 0);
      }
  }
#pragma unroll
  for (int m = 0; m < 4; m++){
    int row0 = m0 + wr*64 + m*16 + g*4;
#pragma unroll
    for (int n = 0; n < 4; n++){
      int col = n0 + wc*64 + n*16 + r15;
#pragma unroll
      for (int r = 0; r < 4; r++){
        float v = acc[m][n][r];
        size_t o = (size_t)(row0 + r)*N + col;
        if (addsrc) v += addsrc[o];
        C[o] = v;
      }
    }
  }
}

// ===== indexer scores via split-bf16 MFMA, triangular 128x128 tiles =====
__global__ __launch_bounds__(256) void iscores_b3(
    const ushort* __restrict__ iqh, const ushort* __restrict__ iql,  // [T,16,128]
    const ushort* __restrict__ ikh, const ushort* __restrict__ ikl,  // [T,128]
    const float* __restrict__ idx_w,                                 // [T,16]
    float* __restrict__ sc){                                         // [T,T]
  int sb = blockIdx.x, tb = blockIdx.y;
  if (sb > tb) return;
  int t0 = tb*128, s0 = sb*128;
  __shared__ __align__(16) ushort Ahs[5120], Als[5120];
  __shared__ __align__(16) ushort Bhs[5120], Bls[5120];
  __shared__ float wlds[128][17];
  int tid = threadIdx.x, lane = tid & 63, w = tid >> 6;
  int wr = w >> 1, wc = w & 1;
  int r15 = lane & 15, g = lane >> 4;
  int srow = tid >> 1, sh = (tid & 1) << 4;
  for (int i = tid; i < 2048; i += 256){
    int r = i >> 4, hh = i & 15;
    wlds[r][hh] = idx_w[(size_t)(t0+r)*16 + hh];
  }
  int soff = srow*40 + sh;
  int aoff[4], boff[4];
#pragma unroll
  for (int m = 0; m < 4; m++){
    aoff[m] = (wr*64 + m*16 + r15)*40 + g*8;
    boff[m] = (wc*64 + m*16 + r15)*40 + g*8;
  }
  float4v sco[4][4];
#pragma unroll
  for (int i=0;i<4;i++)
#pragma unroll
    for (int j=0;j<4;j++) sco[i][j] = (float4v){0.f,0.f,0.f,0.f};
  for (int h = 0; h < 16; h++){
    float4v acc[4][4];
#pragma unroll
    for (int i=0;i<4;i++)
#pragma unroll
      for (int j=0;j<4;j++) acc[i][j] = (float4v){0.f,0.f,0.f,0.f};
    size_t arow = ((size_t)(t0 + srow)*16 + h)*128 + sh;
    size_t brow = (size_t)(s0 + srow)*128 + sh;
    short8 ah0 = *(const short8*)(iqh + arow);
    short8 ah1 = *(const short8*)(iqh + arow + 8);
    short8 al0 = *(const short8*)(iql + arow);
    short8 al1 = *(const short8*)(iql + arow + 8);
    short8 bh0 = *(const short8*)(ikh + brow);
    short8 bh1 = *(const short8*)(ikh + brow + 8);
    short8 bl0 = *(const short8*)(ikl + brow);
    short8 bl1 = *(const short8*)(ikl + brow + 8);
    for (int kt = 0; kt < 4; kt++){
      __syncthreads();
      *(short8*)&Ahs[soff] = ah0; *(short8*)&Ahs[soff+8] = ah1;
      *(short8*)&Als[soff] = al0; *(short8*)&Als[soff+8] = al1;
      *(short8*)&Bhs[soff] = bh0; *(short8*)&Bhs[soff+8] = bh1;
      *(short8*)&Bls[soff] = bl0; *(short8*)&Bls[soff+8] = bl1;
      __syncthreads();
      if (kt < 3){
        int k0 = (kt+1) << 5;
        ah0 = *(const short8*)(iqh + arow + k0);
        ah1 = *(const short8*)(iqh + arow + k0 + 8);
        al0 = *(const short8*)(iql + arow + k0);
        al1 = *(const short8*)(iql + arow + k0 + 8);
        bh0 = *(const short8*)(ikh + brow + k0);
        bh1 = *(const short8*)(ikh + brow + k0 + 8);
        bl0 = *(const short8*)(ikl + brow + k0);
        bl1 = *(const short8*)(ikl + brow + k0 + 8);
      }
      short8 avh[4], avl[4], bvh[4], bvl[4];
#pragma unroll
      for (int m = 0; m < 4; m++){
        avh[m] = *(const short8*)&Ahs[aoff[m]];
        avl[m] = *(const short8*)&Als[aoff[m]];
      }
#pragma unroll
      for (int n = 0; n < 4; n++){
        bvh[n] = *(const short8*)&Bhs[boff[n]];
        bvl[n] = *(const short8*)&Bls[boff[n]];
      }
#pragma unroll
      for (int m = 0; m < 4; m++)
#pragma unroll
        for (int n = 0; n < 4; n++){
          acc[m][n] = __builtin_amdgcn_mfma_f32_16x16x32_bf16(avh[m], bvh[n], acc[m][n], 0, 0, 0);
          acc[m][n] = __builtin_amdgcn_mfma_f32_16x16x32_bf16(avl[m], bvh[n], acc[m][n], 0, 0, 0);
          acc[m][n] = __builtin_amdgcn_mfma_f32_16x16x32_bf16(avh[m], bvl[n], acc[m][n], 0, 0, 0);
        }
    }
#pragma unroll
    for (int m = 0; m < 4; m++){
      int rbase = wr*64 + m*16 + g*4;
#pragma unroll
      for (int r = 0; r < 4; r++){
        float wv = wlds[rbase + r][h];
#pragma unroll
        for (int n = 0; n < 4; n++)
          sco[m][n][r] += wv * fmaxf(acc[m][n][r], 0.f);
      }
    }
  }
#pragma unroll
  for (int m = 0; m < 4; m++){
    int row0 = t0 + wr*64 + m*16 + g*4;
#pragma unroll
    for (int n = 0; n < 4; n++){
      int col = s0 + wc*64 + n*16 + r15;
#pragma unroll
      for (int r = 0; r < 4; r++)
        sc[(size_t)(row0 + r)*2048 + col] = sco[m][n][r];
    }
  }
}

// ===== reg-staged bf16 MFMA GEMM with register prefetch =====
template<int OUTBF>
__global__ __launch_bounds__(256) void gemm_bf16s(
    const ushort* __restrict__ A, const ushort* __restrict__ Bt,
    float* __restrict__ Cf, ushort* __restrict__ Cb,
    const float* __restrict__ addsrc, int N, int K){
  __shared__ __align__(16) ushort As[5120];
  __shared__ __align__(16) ushort Bs[5120];
  int tid = threadIdx.x, lane = tid & 63, w = tid >> 6;
  int m0 = blockIdx.y*128, n0 = blockIdx.x*128;
  int wr = w >> 1, wc = w & 1;
  int r15 = lane & 15, g = lane >> 4;
  int srow = tid >> 1, sh = (tid & 1) << 4;
  const ushort* Ag = A + (size_t)(m0 + srow)*K + sh;
  const ushort* Bg = Bt + (size_t)(n0 + srow)*K + sh;
  ushort* Asw = &As[srow*40 + sh];
  ushort* Bsw = &Bs[srow*40 + sh];
  int aoff[4], boff[4];
#pragma unroll
  for (int m = 0; m < 4; m++){
    aoff[m] = (wr*64 + m*16 + r15)*40 + g*8;
    boff[m] = (wc*64 + m*16 + r15)*40 + g*8;
  }
  float4v acc[4][4];
#pragma unroll
  for (int i=0;i<4;i++)
#pragma unroll
    for (int j=0;j<4;j++) acc[i][j] = (float4v){0.f,0.f,0.f,0.f};
  int nk = K >> 5;
  short8 a0 = *(const short8*)(Ag);
  short8 a1 = *(const short8*)(Ag + 8);
  short8 b0 = *(const short8*)(Bg);
  short8 b1 = *(const short8*)(Bg + 8);
  for (int kt = 0; kt < nk; kt++){
    __syncthreads();
    *(short8*)Asw = a0; *(short8*)(Asw + 8) = a1;
    *(short8*)Bsw = b0; *(short8*)(Bsw + 8) = b1;
    __syncthreads();
    if (kt+1 < nk){
      int k0 = (kt+1) << 5;
      a0 = *(const short8*)(Ag + k0);
      a1 = *(const short8*)(Ag + k0 + 8);
      b0 = *(const short8*)(Bg + k0);
      b1 = *(const short8*)(Bg + k0 + 8);
    }
    short8 av[4], bv[4];
#pragma unroll
    for (int m = 0; m < 4; m++) av[m] = *(const short8*)&As[aoff[m]];
#pragma unroll
    for (int n = 0; n < 4; n++) bv[n] = *(const short8*)&Bs[boff[n]];
#pragma unroll
    for (int m = 0; m < 4; m++)
#pragma unroll
      for (int n = 0; n < 4; n++)
        acc[m][n] = __builtin_amdgcn_mfma_f32_16x16x32_bf16(av[m], bv[n], acc[m][n], 0, 0, 0);
  }
#pragma unroll
  for (int m = 0; m < 4; m++){
    int row0 = m0 + wr*64 + m*16 + g*4;
#pragma unroll
    for (int n = 0; n < 4; n++){
      int col = n0 + wc*64 + n*16 + r15;
#pragma unroll
      for (int r = 0; r < 4; r++){
        float v = acc[m][n][r];
        size_t o = (size_t)(row0 + r)*N + col;
        if (addsrc) v += addsrc[o];
        if (OUTBF) Cb[o] = f2bf(v);
        else       Cf[o] = v;
      }
    }
  }
}

// ===== MoE GEMM1 (gathered rows of h2_bf) -> gu fp32, prefetch =====
__global__ __launch_bounds__(256) void moe_gemm1s(
    const ushort* __restrict__ h2bf, const ushort* __restrict__ wgut,
    const int* __restrict__ ecnt, const int* __restrict__ elist,
    float* __restrict__ gu){
  int e = blockIdx.z;
  int count = ecnt[e];
  int r0 = blockIdx.y*128;
  if (r0 >= count) return;
  __shared__ int rows[128];
  __shared__ __align__(16) ushort As[5120];
  __shared__ __align__(16) ushort Bs[5120];
  int tid = threadIdx.x, lane = tid & 63, w = tid >> 6;
  int n0 = blockIdx.x*128;
  if (tid < 128) rows[tid] = (r0 + tid < count) ? elist[e*2048 + r0 + tid] : -1;
  __syncthreads();
  int wr = w >> 1, wc = w & 1;
  int r15 = lane & 15, g = lane >> 4;
  int srow = tid >> 1, sh = (tid & 1) << 4;
  int ent0 = rows[srow];
  int tok = (ent0 >= 0) ? (ent0 >> 2) : 0;
  const ushort* Ag = h2bf + (size_t)tok*2048 + sh;
  const ushort* Bg = wgut + ((size_t)e*1024 + n0 + srow)*2048 + sh;
  ushort* Asw = &As[srow*40 + sh];
  ushort* Bsw = &Bs[srow*40 + sh];
  int aoff[4], boff[4];
#pragma unroll
  for (int m = 0; m < 4; m++){
    aoff[m] = (wr*64 + m*16 + r15)*40 + g*8;
    boff[m] = (wc*64 + m*16 + r15)*40 + g*8;
  }
  float4v acc[4][4];
#pragma unroll
  for (int i=0;i<4;i++)
#pragma unroll
    for (int j=0;j<4;j++) acc[i][j] = (float4v){0.f,0.f,0.f,0.f};
  short8 a0 = *(const short8*)(Ag);
  short8 a1 = *(const short8*)(Ag + 8);
  short8 b0 = *(const short8*)(Bg);
  short8 b1 = *(const short8*)(Bg + 8);
  for (int kt = 0; kt < 64; kt++){
    __syncthreads();
    *(short8*)Asw = a0; *(short8*)(Asw + 8) = a1;
    *(short8*)Bsw = b0; *(short8*)(Bsw + 8) = b1;
    __syncthreads();
    if (kt < 63){
      int k0 = (kt+1) << 5;
      a0 = *(const short8*)(Ag + k0);
      a1 = *(const short8*)(Ag + k0 + 8);
      b0 = *(const short8*)(Bg + k0);
      b1 = *(const short8*)(Bg + k0 + 8);
    }
    short8 av[4], bv[4];
#pragma unroll
    for (int m = 0; m < 4; m++) av[m] = *(const short8*)&As[aoff[m]];
#pragma unroll
    for (int n = 0; n < 4; n++) bv[n] = *(const short8*)&Bs[boff[n]];
#pragma unroll
    for (int m = 0; m < 4; m++)
#pragma unroll
      for (int n = 0; n < 4; n++)
        acc[m][n] = __builtin_amdgcn_mfma_f32_16x16x32_bf16(av[m], bv[n], acc[m][n], 0, 0, 0);
  }
#pragma unroll
  for (int m = 0; m < 4; m++){
#pragma unroll
    for (int r = 0; r < 4; r++){
      int ent = rows[wr*64 + m*16 + g*4 + r];
      if (ent < 0) continue;
#pragma unroll
      for (int n = 0; n < 4; n++){
        int col = n0 + wc*64 + n*16 + r15;
        gu[(size_t)ent*1024 + col] = acc[m][n][r];
      }
    }
  }
}

// ===== MoE GEMM2: act_bf -> down fp32 (x tw), prefetch =====
__global__ __launch_bounds__(256) void moe_gemm2s(
    const ushort* __restrict__ act, const ushort* __restrict__ wdt,
    const int* __restrict__ ecnt, const int* __restrict__ elist,
    const float* __restrict__ tw, float* __restrict__ down){
  int e = blockIdx.z;
  int count = ecnt[e];
  int r0 = blockIdx.y*128;
  if (r0 >= count) return;
  __shared__ int rows[128];
  __shared__ __align__(16) ushort As[5120];
  __shared__ __align__(16) ushort Bs[5120];
  int tid = threadIdx.x, lane = tid & 63, w = tid >> 6;
  int n0 = blockIdx.x*128;
  if (tid < 128) rows[tid] = (r0 + tid < count) ? elist[e*2048 + r0 + tid] : -1;
  __syncthreads();
  int wr = w >> 1, wc = w & 1;
  int r15 = lane & 15, g = lane >> 4;
  int srow = tid >> 1, sh = (tid & 1) << 4;
  int ent0 = rows[srow];
  int src = (ent0 >= 0) ? ent0 : 0;
  const ushort* Ag = act + (size_t)src*512 + sh;
  const ushort* Bg = wdt + ((size_t)e*2048 + n0 + srow)*512 + sh;
  ushort* Asw = &As[srow*40 + sh];
  ushort* Bsw = &Bs[srow*40 + sh];
  int aoff[4], boff[4];
#pragma unroll
  for (int m = 0; m < 4; m++){
    aoff[m] = (wr*64 + m*16 + r15)*40 + g*8;
    boff[m] = (wc*64 + m*16 + r15)*40 + g*8;
  }
  float4v acc[4][4];
#pragma unroll
  for (int i=0;i<4;i++)
#pragma unroll
    for (int j=0;j<4;j++) acc[i][j] = (float4v){0.f,0.f,0.f,0.f};
  short8 a0 = *(const short8*)(Ag);
  short8 a1 = *(const short8*)(Ag + 8);
  short8 b0 = *(const short8*)(Bg);
  short8 b1 = *(const short8*)(Bg + 8);
  for (int kt = 0; kt < 16; kt++){
    __syncthreads();
    *(short8*)Asw = a0; *(short8*)(Asw + 8) = a1;
    *(short8*)Bsw = b0; *(short8*)(Bsw + 8) = b1;
    __syncthreads();
    if (kt < 15){
      int k0 = (kt+1) << 5;
      a0 = *(const short8*)(Ag + k0);
      a1 = *(const short8*)(Ag + k0 + 8);
      b0 = *(const short8*)(Bg + k0);
      b1 = *(const short8*)(Bg + k0 + 8);
    }
    short8 av[4], bv[4];
#pragma unroll
    for (int m = 0; m < 4; m++) av[m] = *(const short8*)&As[aoff[m]];
#pragma unroll
    for (int n = 0; n < 4; n++) bv[n] = *(const short8*)&Bs[boff[n]];
#pragma unroll
    for (int m = 0; m < 4; m++)
#pragma unroll
      for (int n = 0; n < 4; n++)
        acc[m][n] = __builtin_amdgcn_mfma_f32_16x16x32_bf16(av[m], bv[n], acc[m][n], 0, 0, 0);
  }
#pragma unroll
  for (int m = 0; m < 4; m++){
#pragma unroll
    for (int r = 0; r < 4; r++){
      int ent = rows[wr*64 + m*16 + g*4 + r];
      if (ent < 0) continue;
      float wgt = tw[ent];
#pragma unroll
      for (int n = 0; n < 4; n++){
        int col = n0 + wc*64 + n*16 + r15;
        down[(size_t)ent*2048 + col] = acc[m][n][r]*wgt;
      }
    }
  }
}

// ---------------- top-k (stable ties) ----------------
__global__ __launch_bounds__(256) void topk_kernel(
    const float* __restrict__ scores, int* __restrict__ list, int* __restrict__ cnt){
  int t = blockIdx.x, tid = threadIdx.x;
  if (t < ITOPKk){
    for (int i = tid; i <= t; i += 256) list[(size_t)t*ITOPKk + i] = i;
    if (tid==0) cnt[t] = t+1;
    return;
  }
  int n = t+1;
  const float* row = scores + (size_t)t*2048;
  __shared__ unsigned hist[256];
  __shared__ unsigned sh_prefix, sh_krem;
  __shared__ int scan[256];
  __shared__ int sh_base_sel, sh_base_eq;
  if (tid==0){ sh_prefix = 0u; sh_krem = ITOPKk; }
  __syncthreads();
  for (int level = 3; level >= 0; level--){
    int shift = level*8;
    hist[tid] = 0u; __syncthreads();
    unsigned pfx = sh_prefix;
    for (int s = tid; s < n; s += 256){
      unsigned u = mapf(row[s]);
      bool ok = (level==3) || ((u >> (shift+8)) == pfx);
      if (ok) atomicAdd(&hist[(u >> shift) & 255u], 1u);
    }
    __syncthreads();
    if (tid==0){
      unsigned krem = sh_krem, c = 0u; int bsel = 0;
      for (int b = 255; b >= 0; b--){
        if (c + hist[b] >= krem){ bsel = b; break; }
        c += hist[b];
      }
      sh_prefix = (pfx << 8) | (unsigned)bsel;
      sh_krem = krem - c;
    }
    __syncthreads();
  }
  unsigned uth = sh_prefix; int R = (int)sh_krem;
  if (tid==0){ sh_base_sel = 0; sh_base_eq = 0; }
  __syncthreads();
  for (int c0 = 0; c0 < n; c0 += 256){
    int s = c0 + tid;
    unsigned u = (s < n) ? mapf(row[s]) : 0u;
    int gt = (s < n) && (u > uth);
    int eq = (s < n) && (u == uth);
    scan[tid] = (eq << 16) | gt; __syncthreads();
    for (int off = 1; off < 256; off <<= 1){
      int v = (tid >= off) ? scan[tid-off] : 0; __syncthreads();
      scan[tid] += v; __syncthreads();
    }
    int incl = scan[tid];
    int gt_incl = incl & 0xffff, eq_incl = incl >> 16;
    int gt_excl = gt_incl - gt, eq_excl = eq_incl - eq;
    int tot = scan[255]; int gt_tot = tot & 0xffff, eq_tot = tot >> 16;
    int base_sel = sh_base_sel, base_eq = sh_base_eq;
    int rtake = R - base_eq; if (rtake < 0) rtake = 0;
    bool selected = gt || (eq && eq_excl < rtake);
    int pos = base_sel + gt_excl + min(eq_excl, rtake);
    if (selected) list[(size_t)t*ITOPKk + pos] = s;
    __syncthreads();
    if (tid==0){
      sh_base_sel = base_sel + gt_tot + min(eq_tot, rtake);
      sh_base_eq  = base_eq + eq_tot;
    }
    __syncthreads();
  }
  if (tid==0) cnt[t] = ITOPKk;
}

// ---------------- sparse attention (fp32), XCD-aware ----------------------
// QK: 16 lanes per (s,head) dot -> 4-step width-16 shuffle tree. PV: 4 accs.
#define HG 2
__global__ __launch_bounds__(256) void attn_kernel(
    const float* __restrict__ q, const float* __restrict__ kv,
    const float* __restrict__ kpe,
    const int* __restrict__ list, const int* __restrict__ cnt,
    ushort* __restrict__ at_hi, ushort* __restrict__ at_lo){
  int b = blockIdx.x;
  int g8 = b & 7, t = b >> 3;
  int h0 = g8*HG;
  int tid = threadIdx.x, lane = tid & 63, w = tid >> 6;
  __shared__ int   sl[ITOPKk];
  __shared__ float qs[HG][200];
  __shared__ float lg[HG][ITOPKk];
  __shared__ float redm[4], reds[4];
  __shared__ float4 outp4[8][32];
  int n = cnt[t];
  for (int i = tid; i < n; i += 256) sl[i] = list[(size_t)t*ITOPKk + i];
  for (int i = tid; i < HG*192; i += 256){
    int hh = i/192, d = i - hh*192;
    qs[hh][d] = q[(size_t)t*(NHEAD*QKDd) + (h0+hh)*QKDd + d];
  }
  __syncthreads();
  const float scale = 0.07216878364870323f;
  int half = lane >> 5, l4 = lane & 15, grp = (lane >> 4) & 1;
  float4 qv0 = *(const float4*)&qs[half][l4*8];
  float4 qv1 = *(const float4*)&qs[half][l4*8 + 4];
  float4 qp  = *(const float4*)&qs[half][128 + l4*4];
  size_t koff = (size_t)(h0+half)*256 + (size_t)l4*8;
  size_t poff = (size_t)l4*4;
  for (int i0 = w*4; i0 < n; i0 += 16){
    int idx0 = i0 + grp, idx1 = i0 + grp + 2;
    int e0 = (idx0 < n) ? idx0 : n-1;
    int e1 = (idx1 < n) ? idx1 : n-1;
    int s0 = sl[e0], s1 = sl[e1];
    float4 k00 = *(const float4*)(kv + (size_t)s0*4096 + koff);
    float4 k01 = *(const float4*)(kv + (size_t)s0*4096 + koff + 4);
    float4 p0  = *(const float4*)(kpe + (size_t)s0*64 + poff);
    float4 k10 = *(const float4*)(kv + (size_t)s1*4096 + koff);
    float4 k11 = *(const float4*)(kv + (size_t)s1*4096 + koff + 4);
    float4 p1  = *(const float4*)(kpe + (size_t)s1*64 + poff);
    float d0 = k00.x*qv0.x + k00.y*qv0.y + k00.z*qv0.z + k00.w*qv0.w
             + k01.x*qv1.x + k01.y*qv1.y + k01.z*qv1.z + k01.w*qv1.w
             + p0.x*qp.x + p0.y*qp.y + p0.z*qp.z + p0.w*qp.w;
    float d1 = k10.x*qv0.x + k10.y*qv0.y + k10.z*qv0.z + k10.w*qv0.w
             + k11.x*qv1.x + k11.y*qv1.y + k11.z*qv1.z + k11.w*qv1.w
             + p1.x*qp.x + p1.y*qp.y + p1.z*qp.z + p1.w*qp.w;
#pragma unroll
    for (int off = 8; off > 0; off >>= 1){
      d0 += __shfl_down(d0, off, 16);
      d1 += __shfl_down(d1, off, 16);
    }
    if (l4 == 0){
      if (idx0 < n) lg[half][idx0] = d0*scale;
      if (idx1 < n) lg[half][idx1] = d1*scale;
    }
  }
  __syncthreads();
  int slice = tid & 31, sg = tid >> 5;
  for (int hh = 0; hh < HG; hh++){
    int h = h0 + hh;
    float mx = NEGINF;
    for (int i = tid; i < n; i += 256) mx = fmaxf(mx, lg[hh][i]);
    mx = warp_max(mx);
    if (lane==0) redm[w] = mx;
    __syncthreads();
    mx = fmaxf(fmaxf(redm[0],redm[1]), fmaxf(redm[2],redm[3]));
    float sum = 0.f;
    for (int i = tid; i < n; i += 256){ float p = expf(lg[hh][i]-mx); lg[hh][i] = p; sum += p; }
    sum = warp_sum(sum);
    if (lane==0) reds[w] = sum;
    __syncthreads();
    float inv = 1.f/(reds[0]+reds[1]+reds[2]+reds[3]);
    float4 a0 = {0,0,0,0}, a1 = {0,0,0,0}, a2 = {0,0,0,0}, a3 = {0,0,0,0};
    size_t voff = (size_t)h*256 + 128 + slice*4;
    int i = sg;
    for (; i + 24 < n; i += 32){
      float pA = lg[hh][i];
      float4 vA = *(const float4*)(kv + (size_t)sl[i]*4096 + voff);
      float pB = lg[hh][i+8];
      float4 vB = *(const float4*)(kv + (size_t)sl[i+8]*4096 + voff);
      float pC = lg[hh][i+16];
      float4 vC = *(const float4*)(kv + (size_t)sl[i+16]*4096 + voff);
      float pD = lg[hh][i+24];
      float4 vD = *(const float4*)(kv + (size_t)sl[i+24]*4096 + voff);
      a0.x += pA*vA.x; a0.y += pA*vA.y; a0.z += pA*vA.z; a0.w += pA*vA.w;
      a1.x += pB*vB.x; a1.y += pB*vB.y; a1.z += pB*vB.z; a1.w += pB*vB.w;
      a2.x += pC*vC.x; a2.y += pC*vC.y; a2.z += pC*vC.z; a2.w += pC*vC.w;
      a3.x += pD*vD.x; a3.y += pD*vD.y; a3.z += pD*vD.z; a3.w += pD*vD.w;
    }
    for (; i < n; i += 8){
      float p = lg[hh][i];
      float4 v4 = *(const float4*)(kv + (size_t)sl[i]*4096 + voff);
      a0.x += p*v4.x; a0.y += p*v4.y; a0.z += p*v4.z; a0.w += p*v4.w;
    }
    float4 acc;
    acc.x = (a0.x + a1.x) + (a2.x + a3.x);
    acc.y = (a0.y + a1.y) + (a2.y + a3.y);
    acc.z = (a0.z + a1.z) + (a2.z + a3.z);
    acc.w = (a0.w + a1.w) + (a2.w + a3.w);
    outp4[sg][slice] = acc;
    __syncthreads();
    if (tid < 32){
      float4 r = outp4[0][tid];
#pragma unroll
      for (int gg = 1; gg < 8; gg++){
        float4 o = outp4[gg][tid];
        r.x += o.x; r.y += o.y; r.z += o.z; r.w += o.w;
      }
      r.x *= inv; r.y *= inv; r.z *= inv; r.w *= inv;
      size_t o = (size_t)t*2048 + h*128 + tid*4;
      ushort4 hi4, lo4;
      hi4.x = f2bf(r.x); lo4.x = f2bf(r.x - bf2f(hi4.x));
      hi4.y = f2bf(r.y); lo4.y = f2bf(r.y - bf2f(hi4.y));
      hi4.z = f2bf(r.z); lo4.z = f2bf(r.z - bf2f(hi4.z));
      hi4.w = f2bf(r.w); lo4.w = f2bf(r.w - bf2f(hi4.w));
      *(ushort4*)&at_hi[o] = hi4;
      *(ushort4*)&at_lo[o] = lo4;
    }
    __syncthreads();
  }
}

// ---------------- gate ----------------
__global__ void gate_kernel(const float* __restrict__ glog, float* __restrict__ tw,
                            int* __restrict__ ecnt, int* __restrict__ elist){
  int t = blockIdx.x*256 + threadIdx.x;
  if (t >= T_TOK) return;
  float g[8]; float mx = NEGINF;
  for (int i = 0; i < 8; i++){ g[i] = glog[t*8+i]; mx = fmaxf(mx, g[i]); }
  float s = 0.f;
  for (int i = 0; i < 8; i++){ g[i] = expf(g[i]-mx); s += g[i]; }
  for (int i = 0; i < 8; i++) g[i] /= s;
  bool used[8] = {};
  float tv[4]; int si[4];
  for (int k = 0; k < 4; k++){
    float best = -1.f; int bi = 0;
    for (int i = 0; i < 8; i++) if (!used[i] && g[i] > best){ best = g[i]; bi = i; }
    used[bi] = true; tv[k] = best; si[k] = bi;
  }
  float s4 = tv[0]+tv[1]+tv[2]+tv[3];
  for (int k = 0; k < 4; k++){
    tw[t*4+k] = tv[k]/s4;
    int pos = atomicAdd(&ecnt[si[k]], 1);
    elist[si[k]*2048 + pos] = t*4+k;
  }
}

// ---------------- MoE silu: gu [8192,1024] -> act bf16 [8192,512] ----------------
__global__ __launch_bounds__(256) void silu_moe(const float* __restrict__ gu,
                                                ushort* __restrict__ act){
  int i = blockIdx.x*256 + threadIdx.x;
  if (i >= 8192*128) return;
  int row = i >> 7, jc = i & 127;
  float4 g4 = ((const float4*)(gu + (size_t)row*1024))[jc];
  float4 u4 = ((const float4*)(gu + (size_t)row*1024 + 512))[jc];
  ushort4 o;
  o.x = f2bf(g4.x/(1.f+expf(-g4.x))*u4.x);
  o.y = f2bf(g4.y/(1.f+expf(-g4.y))*u4.y);
  o.z = f2bf(g4.z/(1.f+expf(-g4.z))*u4.z);
  o.w = f2bf(g4.w/(1.f+expf(-g4.w))*u4.w);
  ((ushort4*)(act + (size_t)row*512))[jc] = o;
}

// ---------------- combine: out_final += sum of 4 expert slots ----------------
__global__ __launch_bounds__(256) void moe_combine(const float* __restrict__ down,
                                                   float* __restrict__ outf){
  int t = blockIdx.x;
  size_t base = (size_t)t*4*2048;
  for (int d = threadIdx.x; d < 2048; d += 256){
    float s = down[base+d] + down[base+2048+d] + down[base+4096+d] + down[base+6144+d];
    outf[(size_t)t*2048 + d] += s;
  }
}

// ---------------- shared-expert silu -> bf16 ----------------
__global__ __launch_bounds__(256) void silu_sh(const float* __restrict__ sgu,
                                               ushort* __restrict__ shact){
  int i = blockIdx.x*256 + threadIdx.x;
  if (i >= 2048*256) return;
  int row = i >> 8, jc = i & 255;
  float4 g4 = ((const float4*)(sgu + (size_t)row*2048))[jc];
  float4 u4 = ((const float4*)(sgu + (size_t)row*2048 + 1024))[jc];
  ushort4 o;
  o.x = f2bf(g4.x/(1.f+expf(-g4.x))*u4.x);
  o.y = f2bf(g4.y/(1.f+expf(-g4.y))*u4.y);
  o.z = f2bf(g4.z/(1.f+expf(-g4.z))*u4.z);
  o.w = f2bf(g4.w/(1.f+expf(-g4.w))*u4.w);
  ((ushort4*)(shact + (size_t)row*1024))[jc] = o;
}

// ---------------- host ----------------
extern "C" void kernel_launch(void* const* d_in, const int* in_sizes, int n_in,
                              void* d_out, int out_size, void* d_ws, size_t ws_size,
                              hipStream_t stream){
  const int*   positions  = (const int*)  d_in[0];
  const float* hidden     = (const float*)d_in[1];
  const float* ln1_w      = (const float*)d_in[2];
  const float* ln2_w      = (const float*)d_in[3];
  const float* w_qkv_a    = (const float*)d_in[4];
  const float* q_a_ln_w   = (const float*)d_in[5];
  const float* kv_a_ln_w  = (const float*)d_in[6];
  const float* w_q_b      = (const float*)d_in[7];
  const float* w_kv_b     = (const float*)d_in[8];
  const float* w_o        = (const float*)d_in[9];
  const float* w_idx_k    = (const float*)d_in[10];
  const float* idx_k_ln_w = (const float*)d_in[11];
  const float* idx_k_ln_b = (const float*)d_in[12];
  const float* w_idx_qb   = (const float*)d_in[13];
  const float* w_idx_w    = (const float*)d_in[14];
  const float* w_gate     = (const float*)d_in[15];
  const float* w_moe_gu   = (const float*)d_in[16];
  const float* w_moe_d    = (const float*)d_in[17];
  const float* w_sh_gu    = (const float*)d_in[18];
  const float* w_sh_d     = (const float*)d_in[19];

  float* out_final = (float*)d_out;                       // [T,2048]
  float* residual  = (float*)d_out + (size_t)T_TOK*HIDN;  // [T,2048]

  float* ws = (float*)d_ws;
  // ---- arena (19,005,440 floats) with phase overlays ----
  float* arena   = ws;
  float* qkv_main= arena;                  // [T,2048]  phase1
  float* qkv_pe  = arena + 4194304;        // [T,64]
  float* iscores = arena;                  // [T,T]     overlays qkv (dead)
  float* qbuf    = arena + 4325376;        // [T,16,192]
  float* idx_q   = arena + 10616832;       // [T,16,128] fp32 (pre-rope)
  float* sgu     = arena;                  // phase2 overlays
  float* gu_buf  = arena;
  float* down_buf= arena;
  ushort* act_bf = (ushort*)(arena + 16777216); // [8192,512] bf16
  // qkv_a/idx_k-step split scratch:
  ushort* h_hi  = (ushort*)(arena + 4325376);   // 4,194,304 ush
  ushort* h_lo  = h_hi + 4194304;
  ushort* wqa_hi= (ushort*)(arena + 8519680);   // 4,325,376 ush
  ushort* wqa_lo= wqa_hi + 4325376;
  ushort* wik_hi= (ushort*)(arena + 12845056);  // 262,144 ush
  ushort* wik_lo= wik_hi + 262144;
  // idx_qb-step weight scratch (clobbers h splits after idx_k gemm):
  ushort* wiq_hi= (ushort*)(arena + 4325376);   // 3,145,728 ush
  ushort* wiq_lo= wiq_hi + 3145728;
  // indexer split buffers:
  ushort* ik_hi = (ushort*)(arena + 4325376);   // 262,144 ush (after idx_qb; wiq dead)
  ushort* ik_lo = ik_hi + 262144;
  ushort* iq_hi = (ushort*)(arena + 14811136);  // 4,194,304 ush
  ushort* iq_lo = iq_hi + 4194304;
  // post-topk scratch:
  ushort* s1 = (ushort*)arena;                  // iscores region
  ushort* s2 = (ushort*)(arena + 10616832);     // idx_q/iq region
  // ---- fixed fp32 tail ----
  size_t off = 19005440;
  float* h      = ws + off; off += 4194304;   // [T,2048]
  float* kv     = ws + off; off += 8388608;   // [T,16,256] fp32 (qc-split overlay first)
  float* attnbuf= ws + off; off += 4194304;   // kvc-split overlay / wmd_t
  float* k_pe   = ws + off; off += 131072;
  float* idx_k  = ws + off; off += 262144;    // [T,128] fp32 (pre-LN)
  float* idx_w  = ws + off; off += 32768;
  float* glog   = ws + off; off += 16384;
  float* tw     = ws + off; off += 8192;
  float* ctab   = ws + off; off += 65536;
  float* stab   = ws + off; off += 65536;
  int* list     = (int*)(ws + off);           // [T,512]
  int* cnt      = list + 1048576;
  int* ecnt     = cnt + 2048;
  int* elist    = ecnt + 8;
  off += 1067016;
  // ---- ushort region ----
  ushort* h2_bf   = (ushort*)(ws + off); off += 2097152;
  ushort* shact_bf= (ushort*)(ws + off); off += 1048576;
  ushort* wshgu_t = (ushort*)(ws + off); off += 2097152;
  ushort* wshd_t  = (ushort*)(ws + off); off += 1048576;   // total 43,722,760 floats
  // overlays on dead tail fp32 buffers:
  ushort* qc_hi  = (ushort*)kv;               // dead until kv_b
  ushort* qc_lo  = qc_hi + 3145728;
  ushort* kvc_hi = (ushort*)attnbuf;          // dead until MoE transposes
  ushort* kvc_lo = kvc_hi + 1048576;
  ushort* wmgu_t = (ushort*)kv;
  ushort* wmd_t  = (ushort*)attnbuf;
  size_t total_bytes = off * sizeof(float);
  if (ws_size < total_bytes) return;

  // post-topk scratch assignments:
  ushort* wqbt_hi= s2;
  ushort* wqbt_lo= s2 + 4718592;
  ushort* wkvt_hi= s1;
  ushort* wkvt_lo= s1 + 2097152;
  ushort* at_hi  = s2;                 // attn writes split output here
  ushort* at_lo  = s2 + 4194304;
  ushort* wot_hi = s1;
  ushort* wot_lo = s1 + 4194304;

  // shared-expert weight transposes (consumed after gate)
  transconv<<<dim3(64,64,1), 256, 0, stream>>>(w_sh_gu, wshgu_t, 2048, 2048);
  transconv<<<dim3(64,32,1), 256, 0, stream>>>(w_sh_d,  wshd_t,  1024, 2048);

  rope_table_kernel<<<T_TOK, 32, 0, stream>>>(positions, ctab, stab);
  // ---- rmsnorm + split fused (h fp32 + h_hi/h_lo) ----
  rmsnorm_both<<<T_TOK, 256, 0, stream>>>(hidden, HIDN, 0, ln1_w, h, h_hi, h_lo, HIDN, HIDN);
  // ---- qkv_a via split-bf16 MFMA (2048 cols) + fp32 (pe 64 cols) ----
  transconv_split<<<dim3(66,64), 256, 0, stream>>>(w_qkv_a, wqa_hi, wqa_lo, 2048, 2112);
  gemm_b3<<<dim3(16,16), 256, 0, stream>>>(h_hi, h_lo, wqa_hi, wqa_lo, qkv_main, nullptr, 2048, 2048);
  gemm_f32<<<dim3(1,32), 256, 0, stream>>>(h, HIDN, w_qkv_a + 2048, 2112, qkv_pe, 64, nullptr, 0, T_TOK, 64, HIDN, 1.f);
  // ---- fused rmsnorm -> split for q_c / kv_c ----
  rmsnorm_split<<<T_TOK, 256, 0, stream>>>(qkv_main, 2048, 0,    q_a_ln_w,  qc_hi,  qc_lo,  QLRr,  QLRr);
  rmsnorm_split<<<T_TOK, 256, 0, stream>>>(qkv_main, 2048, QLRr, kv_a_ln_w, kvc_hi, kvc_lo, KVLRr, KVLRr);
  rope_kpe_kernel<<<T_TOK, 32, 0, stream>>>(qkv_pe, ctab, stab, k_pe);
  // ---- idx_k via split-bf16 MFMA (fp32 pre-LN out) ----
  transconv_split<<<dim3(4,64), 256, 0, stream>>>(w_idx_k, wik_hi, wik_lo, 2048, 128);
  gemm_b3<<<dim3(1,16), 256, 0, stream>>>(h_hi, h_lo, wik_hi, wik_lo, idx_k, nullptr, 128, 2048);
  // ---- idx_qb via split-bf16 MFMA ----
  transconv_split<<<dim3(64,48), 256, 0, stream>>>(w_idx_qb, wiq_hi, wiq_lo, 1536, 2048);
  gemm_b3<<<dim3(16,16), 256, 0, stream>>>(qc_hi, qc_lo, wiq_hi, wiq_lo, idx_q, nullptr, 2048, 1536);
  // ---- fused rope -> split for idx_q ----
  rope_idxq_split<<<T_TOK, 256, 0, stream>>>(idx_q, ctab, stab, iq_hi, iq_lo);
  // ---- fused LN+rope -> split for idx_k (wiq dead now) ----
  ln_rope_idxk_split<<<T_TOK, 128, 0, stream>>>(idx_k, idx_k_ln_w, idx_k_ln_b, ctab, stab, ik_hi, ik_lo);
  // ---- idx_w (tiny fp32) ----
  gemm_f32<<<dim3(1,32), 256, 0, stream>>>(h, HIDN, w_idx_w, INHh, idx_w, INHh, nullptr, 0, T_TOK, INHh, HIDN, 0.02209708691207961f);
  // ---- iscores via split-bf16 MFMA (triangular) ----
  iscores_b3<<<dim3(16,16), 256, 0, stream>>>(iq_hi, iq_lo, ik_hi, ik_lo, idx_w, iscores);
  topk_kernel<<<T_TOK, 256, 0, stream>>>(iscores, list, cnt);
  // ---- q_b via split-bf16 MFMA ----
  transconv_split<<<dim3(96,48), 256, 0, stream>>>(w_q_b, wqbt_hi, wqbt_lo, 1536, 3072);
  gemm_b3<<<dim3(24,16), 256, 0, stream>>>(qc_hi, qc_lo, wqbt_hi, wqbt_lo, qbuf, nullptr, 3072, 1536);
  rope_q_kernel<<<T_TOK, 256, 0, stream>>>(qbuf, ctab, stab);
  // ---- kv_b via split-bf16 MFMA (qc splits dead -> kv fp32 reuse OK) ----
  transconv_split<<<dim3(128,16), 256, 0, stream>>>(w_kv_b, wkvt_hi, wkvt_lo, 512, 4096);
  gemm_b3<<<dim3(32,16), 256, 0, stream>>>(kvc_hi, kvc_lo, wkvt_hi, wkvt_lo, kv, nullptr, 4096, 512);
  // ---- attention (writes split hi/lo output directly) ----
  attn_kernel<<<T_TOK*(NHEAD/HG), 256, 0, stream>>>(qbuf, kv, k_pe, list, cnt, at_hi, at_lo);
  // ---- w_o via split-bf16 MFMA (+hidden -> residual) ----
  transconv_split<<<dim3(64,64), 256, 0, stream>>>(w_o, wot_hi, wot_lo, 2048, 2048);
  gemm_b3<<<dim3(16,16), 256, 0, stream>>>(at_hi, at_lo, wot_hi, wot_lo, residual, hidden, 2048, 2048);
  // kv/attnbuf now dead -> MoE weight transposes into their space
  transconv<<<dim3(32,64,8), 256, 0, stream>>>(w_moe_gu, wmgu_t, 2048, 1024);
  transconv<<<dim3(64,16,8), 256, 0, stream>>>(w_moe_d,  wmd_t,  512,  2048);
  // ---- rmsnorm2 + bf16 fused (h fp32 + h2_bf) ----
  rmsnorm_bfo<<<T_TOK, 256, 0, stream>>>(residual, HIDN, 0, ln2_w, h, h2_bf, HIDN, HIDN);
  gemm_f32<<<dim3(1,32), 256, 0, stream>>>(h, HIDN, w_gate, NEXP, glog, NEXP, nullptr, 0, T_TOK, NEXP, HIDN, 1.f);
  hipMemsetAsync(ecnt, 0, NEXP*sizeof(int), stream);
  gate_kernel<<<8, 256, 0, stream>>>(glog, tw, ecnt, elist);
  // shared expert (arena as sgu)
  gemm_bf16s<0><<<dim3(16,16), 256, 0, stream>>>(h2_bf, wshgu_t, sgu, nullptr, nullptr, 2048, 2048);
  silu_sh<<<2048, 256, 0, stream>>>(sgu, shact_bf);
  gemm_bf16s<0><<<dim3(16,16), 256, 0, stream>>>(shact_bf, wshd_t, out_final, nullptr, nullptr, 2048, 1024);
  // MoE (arena as gu -> act_bf -> down)
  moe_gemm1s<<<dim3(8, 16, NEXP), 256, 0, stream>>>(h2_bf, wmgu_t, ecnt, elist, gu_buf);
  silu_moe<<<4096, 256, 0, stream>>>(gu_buf, act_bf);
  moe_gemm2s<<<dim3(16, 16, NEXP), 256, 0, stream>>>(act_bf, wmd_t, ecnt, elist, tw, down_buf);
  moe_combine<<<T_TOK, 256, 0, stream>>>(down_buf, out_final);
  (void)in_sizes; (void)n_in; (void)out_size;
}

// Round 21
// 2324.660 us; speedup vs baseline: 1.0323x; 1.0005x over previous
//
#include <hip/hip_runtime.h>
#include <cstdint>
#include <cstddef>

#define T_TOK 2048
#define HIDN  2048
#define NHEAD 16
#define QLRr  1536
#define KVLRr 512
#define DNn   128
#define DRr   64
#define DVv   128
#define QKDd  192
#define INHh  16
#define IHDd  128
#define ITOPKk 512
#define NEXP  8
#define MIi   512
#define SHMI  1024
#define EPSF  1e-6f
#define NEGINF (-3.402823466e38f)

typedef __attribute__((ext_vector_type(8))) short short8;
typedef __attribute__((ext_vector_type(4))) float float4v;

// ---------------- helpers ----------------
__device__ __forceinline__ float warp_sum(float v){
#pragma unroll
  for (int off=32; off>0; off>>=1) v += __shfl_down(v, off, 64);
  return v;
}
__device__ __forceinline__ float warp_max(float v){
#pragma unroll
  for (int off=32; off>0; off>>=1) v = fmaxf(v, __shfl_down(v, off, 64));
  return v;
}
__device__ __forceinline__ unsigned mapf(float f){
  unsigned b = __float_as_uint(f);
  if ((b<<1)==0u) b = 0u;
  return (b & 0x80000000u) ? ~b : (b | 0x80000000u);
}
__device__ __forceinline__ ushort f2bf(float f){
  unsigned u = __float_as_uint(f);
  unsigned r = (u + 0x7fffu + ((u>>16)&1u)) >> 16;
  return (ushort)r;
}
__device__ __forceinline__ float bf2f(ushort u){
  return __uint_as_float(((unsigned)u) << 16);
}

// ---------------- rope tables ----------------
__global__ void rope_table_kernel(const int* __restrict__ pos,
                                  float* __restrict__ ct, float* __restrict__ st){
  int t = blockIdx.x, j = threadIdx.x;          // blockDim 32
  float inv = powf(10000.0f, -(float)j * (1.0f/32.0f));
  float f = (float)pos[t] * inv;
  ct[t*32+j] = cosf(f);
  st[t*32+j] = sinf(f);
}

// ---------------- rmsnorm (fp32 out) ----------------
__global__ __launch_bounds__(256) void rmsnorm_kernel(
    const float* __restrict__ x, int xstride, int xoff,
    const float* __restrict__ w, float* __restrict__ out, int ostride, int D){
  int t = blockIdx.x, tid = threadIdx.x;
  const float* xp = x + (size_t)t*xstride + xoff;
  const float4* x4 = (const float4*)xp;
  int D4 = D >> 2;
  float ss = 0.f;
  for (int i = tid; i < D4; i += 256){ float4 v = x4[i]; ss += v.x*v.x+v.y*v.y+v.z*v.z+v.w*v.w; }
  __shared__ float red[4];
  float s = warp_sum(ss);
  int lane = tid & 63, wid = tid >> 6;
  if (lane==0) red[wid] = s;
  __syncthreads();
  if (tid==0) red[0] = red[0]+red[1]+red[2]+red[3];
  __syncthreads();
  float sc = rsqrtf(red[0]/(float)D + EPSF);
  const float4* w4 = (const float4*)w;
  float4* o4 = (float4*)(out + (size_t)t*ostride);
  for (int i = tid; i < D4; i += 256){
    float4 v = x4[i], ww = w4[i];
    float4 r; r.x=v.x*sc*ww.x; r.y=v.y*sc*ww.y; r.z=v.z*sc*ww.z; r.w=v.w*sc*ww.w;
    o4[i] = r;
  }
}

// ---------------- rmsnorm emitting fp32 AND split hi/lo (fused) ------------
__global__ __launch_bounds__(256) void rmsnorm_both(
    const float* __restrict__ x, int xstride, int xoff,
    const float* __restrict__ w, float* __restrict__ out,
    ushort* __restrict__ hi, ushort* __restrict__ lo,
    int ostride, int D){
  int t = blockIdx.x, tid = threadIdx.x;
  const float* xp = x + (size_t)t*xstride + xoff;
  const float4* x4 = (const float4*)xp;
  int D4 = D >> 2;
  float ss = 0.f;
  for (int i = tid; i < D4; i += 256){ float4 v = x4[i]; ss += v.x*v.x+v.y*v.y+v.z*v.z+v.w*v.w; }
  __shared__ float red[4];
  float s = warp_sum(ss);
  int lane = tid & 63, wid = tid >> 6;
  if (lane==0) red[wid] = s;
  __syncthreads();
  if (tid==0) red[0] = red[0]+red[1]+red[2]+red[3];
  __syncthreads();
  float sc = rsqrtf(red[0]/(float)D + EPSF);
  const float4* w4 = (const float4*)w;
  float4* o4 = (float4*)(out + (size_t)t*ostride);
  ushort4* h4 = (ushort4*)(hi + (size_t)t*ostride);
  ushort4* l4 = (ushort4*)(lo + (size_t)t*ostride);
  for (int i = tid; i < D4; i += 256){
    float4 v = x4[i], ww = w4[i];
    float4 r; r.x=v.x*sc*ww.x; r.y=v.y*sc*ww.y; r.z=v.z*sc*ww.z; r.w=v.w*sc*ww.w;
    o4[i] = r;
    ushort4 hh, ll;
    hh.x = f2bf(r.x); ll.x = f2bf(r.x - bf2f(hh.x));
    hh.y = f2bf(r.y); ll.y = f2bf(r.y - bf2f(hh.y));
    hh.z = f2bf(r.z); ll.z = f2bf(r.z - bf2f(hh.z));
    hh.w = f2bf(r.w); ll.w = f2bf(r.w - bf2f(hh.w));
    h4[i] = hh; l4[i] = ll;
  }
}

// ---------------- rmsnorm emitting fp32 AND bf16 (fused) ----------------
__global__ __launch_bounds__(256) void rmsnorm_bfo(
    const float* __restrict__ x, int xstride, int xoff,
    const float* __restrict__ w, float* __restrict__ out,
    ushort* __restrict__ bfo, int ostride, int D){
  int t = blockIdx.x, tid = threadIdx.x;
  const float* xp = x + (size_t)t*xstride + xoff;
  const float4* x4 = (const float4*)xp;
  int D4 = D >> 2;
  float ss = 0.f;
  for (int i = tid; i < D4; i += 256){ float4 v = x4[i]; ss += v.x*v.x+v.y*v.y+v.z*v.z+v.w*v.w; }
  __shared__ float red[4];
  float s = warp_sum(ss);
  int lane = tid & 63, wid = tid >> 6;
  if (lane==0) red[wid] = s;
  __syncthreads();
  if (tid==0) red[0] = red[0]+red[1]+red[2]+red[3];
  __syncthreads();
  float sc = rsqrtf(red[0]/(float)D + EPSF);
  const float4* w4 = (const float4*)w;
  float4* o4 = (float4*)(out + (size_t)t*ostride);
  ushort4* b4 = (ushort4*)(bfo + (size_t)t*ostride);
  for (int i = tid; i < D4; i += 256){
    float4 v = x4[i], ww = w4[i];
    float4 r; r.x=v.x*sc*ww.x; r.y=v.y*sc*ww.y; r.z=v.z*sc*ww.z; r.w=v.w*sc*ww.w;
    o4[i] = r;
    ushort4 o; o.x=f2bf(r.x); o.y=f2bf(r.y); o.z=f2bf(r.z); o.w=f2bf(r.w);
    b4[i] = o;
  }
}

// ---------------- rmsnorm emitting split hi/lo bf16 directly ----------------
__global__ __launch_bounds__(256) void rmsnorm_split(
    const float* __restrict__ x, int xstride, int xoff,
    const float* __restrict__ w, ushort* __restrict__ hi, ushort* __restrict__ lo,
    int ostride, int D){
  int t = blockIdx.x, tid = threadIdx.x;
  const float* xp = x + (size_t)t*xstride + xoff;
  const float4* x4 = (const float4*)xp;
  int D4 = D >> 2;
  float ss = 0.f;
  for (int i = tid; i < D4; i += 256){ float4 v = x4[i]; ss += v.x*v.x+v.y*v.y+v.z*v.z+v.w*v.w; }
  __shared__ float red[4];
  float s = warp_sum(ss);
  int lane = tid & 63, wid = tid >> 6;
  if (lane==0) red[wid] = s;
  __syncthreads();
  if (tid==0) red[0] = red[0]+red[1]+red[2]+red[3];
  __syncthreads();
  float sc = rsqrtf(red[0]/(float)D + EPSF);
  const float4* w4 = (const float4*)w;
  ushort4* h4 = (ushort4*)(hi + (size_t)t*ostride);
  ushort4* l4 = (ushort4*)(lo + (size_t)t*ostride);
  for (int i = tid; i < D4; i += 256){
    float4 v = x4[i], ww = w4[i];
    float4 r; r.x=v.x*sc*ww.x; r.y=v.y*sc*ww.y; r.z=v.z*sc*ww.z; r.w=v.w*sc*ww.w;
    ushort4 hh, ll;
    hh.x = f2bf(r.x); ll.x = f2bf(r.x - bf2f(hh.x));
    hh.y = f2bf(r.y); ll.y = f2bf(r.y - bf2f(hh.y));
    hh.z = f2bf(r.z); ll.z = f2bf(r.z - bf2f(hh.z));
    hh.w = f2bf(r.w); ll.w = f2bf(r.w - bf2f(hh.w));
    h4[i] = hh; l4[i] = ll;
  }
}

// ---------------- k_pe rope (fp32 out) ----------------
__global__ void rope_kpe_kernel(const float* __restrict__ pe,
                                const float* __restrict__ ct, const float* __restrict__ st,
                                float* __restrict__ kpe){
  int t = blockIdx.x, j = threadIdx.x;          // blockDim 32
  const float* x = pe + (size_t)t*64;
  float x1 = x[j], x2 = x[32+j];
  float c = ct[t*32+j], sn = st[t*32+j];
  kpe[t*64+j]    = x1*c - x2*sn;
  kpe[t*64+32+j] = x1*sn + x2*c;
}

// ---------------- idx_k layernorm + rope, emitting split hi/lo ------------
__global__ __launch_bounds__(128) void ln_rope_idxk_split(
    const float* __restrict__ xk, const float* __restrict__ w, const float* __restrict__ b,
    const float* __restrict__ ct, const float* __restrict__ st,
    ushort* __restrict__ hi, ushort* __restrict__ lo){
  int t = blockIdx.x, tid = threadIdx.x;
  float v = xk[(size_t)t*IHDd + tid];
  float s1 = warp_sum(v), s2 = warp_sum(v*v);
  __shared__ float r1[2], r2[2];
  int lane = tid & 63, wid = tid >> 6;
  if (lane==0){ r1[wid]=s1; r2[wid]=s2; }
  __syncthreads();
  float mean = (r1[0]+r1[1]) * (1.f/128.f);
  float var  = (r2[0]+r2[1]) * (1.f/128.f) - mean*mean;
  float y = (v-mean)*rsqrtf(var+EPSF)*w[tid]+b[tid];
  __shared__ float ly[128];
  ly[tid] = y; __syncthreads();
  float o;
  if (tid < 64) o = y;
  else if (tid < 96){ int j = tid-64; o = ly[64+j]*ct[t*32+j] - ly[96+j]*st[t*32+j]; }
  else              { int j = tid-96; o = ly[64+j]*st[t*32+j] + ly[96+j]*ct[t*32+j]; }
  ushort hh = f2bf(o);
  hi[(size_t)t*IHDd + tid] = hh;
  lo[(size_t)t*IHDd + tid] = f2bf(o - bf2f(hh));
}

// ---------------- rope over q ----------------
__global__ __launch_bounds__(256) void rope_q_kernel(float* __restrict__ q,
                                  const float* __restrict__ ct, const float* __restrict__ st){
  int t = blockIdx.x, tid = threadIdx.x;
  __shared__ float c[32], s[32];
  if (tid < 32){ c[tid]=ct[t*32+tid]; s[tid]=st[t*32+tid]; }
  __syncthreads();
  for (int idx = tid; idx < NHEAD*32; idx += 256){
    int hh = idx >> 5, j = idx & 31;
    float* base = q + (size_t)t*(NHEAD*QKDd) + hh*QKDd;
    float x1 = base[DNn+j], x2 = base[DNn+32+j];
    base[DNn+j]    = x1*c[j] - x2*s[j];
    base[DNn+32+j] = x1*s[j] + x2*c[j];
  }
}

// ---------------- rope over idx_q, emitting split hi/lo ----------------
__global__ __launch_bounds__(256) void rope_idxq_split(const float* __restrict__ q,
                                  const float* __restrict__ ct, const float* __restrict__ st,
                                  ushort* __restrict__ hi, ushort* __restrict__ lo){
  int t = blockIdx.x, tid = threadIdx.x;
  __shared__ float c[32], s[32];
  if (tid < 32){ c[tid]=ct[t*32+tid]; s[tid]=st[t*32+tid]; }
  __syncthreads();
  const float* row = q + (size_t)t*2048;
  for (int idx = tid; idx < 2048; idx += 256){
    int d = idx & 127; int base = idx - d;
    float v;
    if (d < 64) v = row[idx];
    else if (d < 96){ int j = d-64; v = row[base+64+j]*c[j] - row[base+96+j]*s[j]; }
    else            { int j = d-96; v = row[base+64+j]*s[j] + row[base+96+j]*c[j]; }
    ushort hh = f2bf(v);
    hi[(size_t)t*2048 + idx] = hh;
    lo[(size_t)t*2048 + idx] = f2bf(v - bf2f(hh));
  }
}

// ---------------- fp32 GEMM, 64x64 tile (small N only) ----------------
__global__ __launch_bounds__(256) void gemm_f32(
    const float* __restrict__ A, int lda,
    const float* __restrict__ B, int ldb,
    float* __restrict__ C, int ldc,
    const float* __restrict__ addsrc, int ldadd,
    int M, int N, int K, float alpha){
  __shared__ float As[16][68];
  __shared__ float Bs[16][68];
  int tid = threadIdx.x;
  int tx = tid & 15, ty = tid >> 4;
  int m0 = blockIdx.y*64, n0 = blockIdx.x*64;
  float acc[4][4] = {};
  for (int k0 = 0; k0 < K; k0 += 16){
#pragma unroll
    for (int i = 0; i < 4; i++){
      int lin = tid + i*256; int r = lin >> 4, c = lin & 15;
      int m = m0 + r;
      As[c][r] = (m < M) ? A[(size_t)m*lda + k0 + c] : 0.f;
    }
#pragma unroll
    for (int i = 0; i < 4; i++){
      int lin = tid + i*256; int kk = lin >> 6, c = lin & 63;
      int n = n0 + c;
      Bs[kk][c] = (n < N) ? B[(size_t)(k0+kk)*ldb + n] : 0.f;
    }
    __syncthreads();
#pragma unroll
    for (int kk = 0; kk < 16; kk++){
      float4 av = *(const float4*)&As[kk][ty*4];
      float4 bv = *(const float4*)&Bs[kk][tx*4];
      float a[4] = {av.x, av.y, av.z, av.w};
      float b[4] = {bv.x, bv.y, bv.z, bv.w};
#pragma unroll
      for (int i = 0; i < 4; i++)
#pragma unroll
        for (int j = 0; j < 4; j++) acc[i][j] += a[i]*b[j];
    }
    __syncthreads();
  }
#pragma unroll
  for (int i = 0; i < 4; i++){
    int m = m0 + ty*4 + i;
    if (m >= M) continue;
#pragma unroll
    for (int j = 0; j < 4; j++){
      int n = n0 + tx*4 + j;
      if (n >= N) continue;
      float v = acc[i][j]*alpha;
      if (addsrc) v += addsrc[(size_t)m*ldadd + n];
      C[(size_t)m*ldc + n] = v;
    }
  }
}

// ---------------- transpose + convert: src[K,N] fp32 -> dst[N,K] bf16 ----------------
__global__ __launch_bounds__(256) void transconv(const float* __restrict__ src0,
                                                 ushort* __restrict__ dst0, int K, int N){
  int e = blockIdx.z;
  const float* src = src0 + (size_t)e*K*N;
  ushort* dst = dst0 + (size_t)e*N*K;
  int k0 = blockIdx.y*32, n0 = blockIdx.x*32;
  __shared__ float tile[32][33];
  int c = threadIdx.x & 31, r = threadIdx.x >> 5;
  for (int rr = r; rr < 32; rr += 8) tile[rr][c] = src[(size_t)(k0+rr)*N + n0 + c];
  __syncthreads();
  for (int rr = r; rr < 32; rr += 8) dst[(size_t)(n0+rr)*K + k0 + c] = f2bf(tile[c][rr]);
}

// ---------------- transpose + split: src[K,N] fp32 -> hi/lo [N,K] bf16 ----------------
__global__ __launch_bounds__(256) void transconv_split(const float* __restrict__ src,
                                                       ushort* __restrict__ dhi,
                                                       ushort* __restrict__ dlo, int K, int N){
  int k0 = blockIdx.y*32, n0 = blockIdx.x*32;
  __shared__ float tile[32][33];
  int c = threadIdx.x & 31, r = threadIdx.x >> 5;
  for (int rr = r; rr < 32; rr += 8) tile[rr][c] = src[(size_t)(k0+rr)*N + n0 + c];
  __syncthreads();
  for (int rr = r; rr < 32; rr += 8){
    float x = tile[c][rr];
    ushort h = f2bf(x);
    ushort l = f2bf(x - bf2f(h));
    size_t o = (size_t)(n0+rr)*K + k0 + c;
    dhi[o] = h; dlo[o] = l;
  }
}

// ===== split-bf16 MFMA GEMM, 64x64 tile, register prefetch =====
// 4 waves (2x2), each wave 2x2 16x16 frags. Grid: (N/64, M/64).
// Same K-order and per-element MFMA sequence as 128-tile version -> bit-identical.
__global__ __launch_bounds__(256) void gemm_b3(
    const ushort* __restrict__ Ah, const ushort* __restrict__ Al,
    const ushort* __restrict__ Bh, const ushort* __restrict__ Bl,
    float* __restrict__ C, const float* __restrict__ addsrc, int N, int K){
  __shared__ __align__(16) ushort Ahs[2560], Als[2560];
  __shared__ __align__(16) ushort Bhs[2560], Bls[2560];
  int tid = threadIdx.x, lane = tid & 63, w = tid >> 6;
  int m0 = blockIdx.y*64, n0 = blockIdx.x*64;
  int wr = w >> 1, wc = w & 1;
  int r15 = lane & 15, g = lane >> 4;
  int srow = tid >> 2, sh = (tid & 3) << 3;   // 64 rows x 32 K, 8 ushorts/thread
  size_t arow = (size_t)(m0 + srow)*K + sh;
  size_t brow = (size_t)(n0 + srow)*K + sh;
  int soff = srow*40 + sh;
  int aoff[2], boff[2];
#pragma unroll
  for (int m = 0; m < 2; m++){
    aoff[m] = (wr*32 + m*16 + r15)*40 + g*8;
    boff[m] = (wc*32 + m*16 + r15)*40 + g*8;
  }
  float4v acc[2][2];
#pragma unroll
  for (int i=0;i<2;i++)
#pragma unroll
    for (int j=0;j<2;j++) acc[i][j] = (float4v){0.f,0.f,0.f,0.f};
  int nk = K >> 5;
  short8 ah0 = *(const short8*)(Ah + arow);
  short8 al0 = *(const short8*)(Al + arow);
  short8 bh0 = *(const short8*)(Bh + brow);
  short8 bl0 = *(const short8*)(Bl + brow);
  for (int kt = 0; kt < nk; kt++){
    __syncthreads();
    *(short8*)&Ahs[soff] = ah0;
    *(short8*)&Als[soff] = al0;
    *(short8*)&Bhs[soff] = bh0;
    *(short8*)&Bls[soff] = bl0;
    __syncthreads();
    if (kt+1 < nk){
      int k0 = (kt+1) << 5;
      ah0 = *(const short8*)(Ah + arow + k0);
      al0 = *(const short8*)(Al + arow + k0);
      bh0 = *(const short8*)(Bh + brow + k0);
      bl0 = *(const short8*)(Bl + brow + k0);
    }
    short8 avh[2], avl[2], bvh[2], bvl[2];
#pragma unroll
    for (int m = 0; m < 2; m++){
      avh[m] = *(const short8*)&Ahs[aoff[m]];
      avl[m] = *(const short8*)&Als[aoff[m]];
    }
#pragma unroll
    for (int n = 0; n < 2; n++){
      bvh[n] = *(const short8*)&Bhs[boff[n]];
      bvl[n] = *(const short8*)&Bls[boff[n]];
    }
#pragma unroll
    for (int m = 0; m < 2; m++)
#pragma unroll
      for (int n = 0; n < 2; n++){
        acc[m][n] = __builtin_amdgcn_mfma_f32_16x16x32_bf16(avh[m], bvh[n], acc[m][n], 0, 0, 0);
        acc[m][n] = __builtin_amdgcn_mfma_f32_16x16x32_bf16(avl[m], bvh[n], acc[m][n], 0, 0, 0);
        acc[m][n] = __builtin_amdgcn_mfma_f32_16x16x32_bf16(avh[m], bvl[n], acc[m][n], 0, 0, 0);
      }
  }
#pragma unroll
  for (int m = 0; m < 2; m++){
    int row0 = m0 + wr*32 + m*16 + g*4;
#pragma unroll
    for (int n = 0; n < 2; n++){
      int col = n0 + wc*32 + n*16 + r15;
#pragma unroll
      for (int r = 0; r < 4; r++){
        float v = acc[m][n][r];
        size_t o = (size_t)(row0 + r)*N + col;
        if (addsrc) v += addsrc[o];
        C[o] = v;
      }
    }
  }
}

// ===== indexer scores via split-bf16 MFMA, triangular 64x64 tiles =====
__global__ __launch_bounds__(256) void iscores_b3(
    const ushort* __restrict__ iqh, const ushort* __restrict__ iql,  // [T,16,128]
    const ushort* __restrict__ ikh, const ushort* __restrict__ ikl,  // [T,128]
    const float* __restrict__ idx_w,                                 // [T,16]
    float* __restrict__ sc){                                         // [T,T]
  int sb = blockIdx.x, tb = blockIdx.y;
  if (sb > tb) return;
  int t0 = tb*64, s0 = sb*64;
  __shared__ __align__(16) ushort Ahs[2560], Als[2560];
  __shared__ __align__(16) ushort Bhs[2560], Bls[2560];
  __shared__ float wlds[64][17];
  int tid = threadIdx.x, lane = tid & 63, w = tid >> 6;
  int wr = w >> 1, wc = w & 1;
  int r15 = lane & 15, g = lane >> 4;
  int srow = tid >> 2, sh = (tid & 3) << 3;
  for (int i = tid; i < 1024; i += 256){
    int r = i >> 4, hh = i & 15;
    wlds[r][hh] = idx_w[(size_t)(t0+r)*16 + hh];
  }
  int soff = srow*40 + sh;
  int aoff[2], boff[2];
#pragma unroll
  for (int m = 0; m < 2; m++){
    aoff[m] = (wr*32 + m*16 + r15)*40 + g*8;
    boff[m] = (wc*32 + m*16 + r15)*40 + g*8;
  }
  float4v sco[2][2];
#pragma unroll
  for (int i=0;i<2;i++)
#pragma unroll
    for (int j=0;j<2;j++) sco[i][j] = (float4v){0.f,0.f,0.f,0.f};
  for (int h = 0; h < 16; h++){
    float4v acc[2][2];
#pragma unroll
    for (int i=0;i<2;i++)
#pragma unroll
      for (int j=0;j<2;j++) acc[i][j] = (float4v){0.f,0.f,0.f,0.f};
    size_t arow = ((size_t)(t0 + srow)*16 + h)*128 + sh;
    size_t brow = (size_t)(s0 + srow)*128 + sh;
    short8 ah0 = *(const short8*)(iqh + arow);
    short8 al0 = *(const short8*)(iql + arow);
    short8 bh0 = *(const short8*)(ikh + brow);
    short8 bl0 = *(const short8*)(ikl + brow);
    for (int kt = 0; kt < 4; kt++){
      __syncthreads();
      *(short8*)&Ahs[soff] = ah0;
      *(short8*)&Als[soff] = al0;
      *(short8*)&Bhs[soff] = bh0;
      *(short8*)&Bls[soff] = bl0;
      __syncthreads();
      if (kt < 3){
        int k0 = (kt+1) << 5;
        ah0 = *(const short8*)(iqh + arow + k0);
        al0 = *(const short8*)(iql + arow + k0);
        bh0 = *(const short8*)(ikh + brow + k0);
        bl0 = *(const short8*)(ikl + brow + k0);
      }
      short8 avh[2], avl[2], bvh[2], bvl[2];
#pragma unroll
      for (int m = 0; m < 2; m++){
        avh[m] = *(const short8*)&Ahs[aoff[m]];
        avl[m] = *(const short8*)&Als[aoff[m]];
      }
#pragma unroll
      for (int n = 0; n < 2; n++){
        bvh[n] = *(const short8*)&Bhs[boff[n]];
        bvl[n] = *(const short8*)&Bls[boff[n]];
      }
#pragma unroll
      for (int m = 0; m < 2; m++)
#pragma unroll
        for (int n = 0; n < 2; n++){
          acc[m][n] = __builtin_amdgcn_mfma_f32_16x16x32_bf16(avh[m], bvh[n], acc[m][n], 0, 0, 0);
          acc[m][n] = __builtin_amdgcn_mfma_f32_16x16x32_bf16(avl[m], bvh[n], acc[m][n], 0, 0, 0);
          acc[m][n] = __builtin_amdgcn_mfma_f32_16x16x32_bf16(avh[m], bvl[n], acc[m][n], 0, 0, 0);
        }
    }
#pragma unroll
    for (int m = 0; m < 2; m++){
      int rbase = wr*32 + m*16 + g*4;
#pragma unroll
      for (int r = 0; r < 4; r++){
        float wv = wlds[rbase + r][h];
#pragma unroll
        for (int n = 0; n < 2; n++)
          sco[m][n][r] += wv * fmaxf(acc[m][n][r], 0.f);
      }
    }
  }
#pragma unroll
  for (int m = 0; m < 2; m++){
    int row0 = t0 + wr*32 + m*16 + g*4;
#pragma unroll
    for (int n = 0; n < 2; n++){
      int col = s0 + wc*32 + n*16 + r15;
#pragma unroll
      for (int r = 0; r < 4; r++)
        sc[(size_t)(row0 + r)*2048 + col] = sco[m][n][r];
    }
  }
}

// ===== reg-staged bf16 MFMA GEMM, 64x64 tile, register prefetch =====
template<int OUTBF>
__global__ __launch_bounds__(256) void gemm_bf16s(
    const ushort* __restrict__ A, const ushort* __restrict__ Bt,
    float* __restrict__ Cf, ushort* __restrict__ Cb,
    const float* __restrict__ addsrc, int N, int K){
  __shared__ __align__(16) ushort As[2560];
  __shared__ __align__(16) ushort Bs[2560];
  int tid = threadIdx.x, lane = tid & 63, w = tid >> 6;
  int m0 = blockIdx.y*64, n0 = blockIdx.x*64;
  int wr = w >> 1, wc = w & 1;
  int r15 = lane & 15, g = lane >> 4;
  int srow = tid >> 2, sh = (tid & 3) << 3;
  const ushort* Ag = A + (size_t)(m0 + srow)*K + sh;
  const ushort* Bg = Bt + (size_t)(n0 + srow)*K + sh;
  ushort* Asw = &As[srow*40 + sh];
  ushort* Bsw = &Bs[srow*40 + sh];
  int aoff[2], boff[2];
#pragma unroll
  for (int m = 0; m < 2; m++){
    aoff[m] = (wr*32 + m*16 + r15)*40 + g*8;
    boff[m] = (wc*32 + m*16 + r15)*40 + g*8;
  }
  float4v acc[2][2];
#pragma unroll
  for (int i=0;i<2;i++)
#pragma unroll
    for (int j=0;j<2;j++) acc[i][j] = (float4v){0.f,0.f,0.f,0.f};
  int nk = K >> 5;
  short8 a0 = *(const short8*)(Ag);
  short8 b0 = *(const short8*)(Bg);
  for (int kt = 0; kt < nk; kt++){
    __syncthreads();
    *(short8*)Asw = a0;
    *(short8*)Bsw = b0;
    __syncthreads();
    if (kt+1 < nk){
      int k0 = (kt+1) << 5;
      a0 = *(const short8*)(Ag + k0);
      b0 = *(const short8*)(Bg + k0);
    }
    short8 av[2], bv[2];
#pragma unroll
    for (int m = 0; m < 2; m++) av[m] = *(const short8*)&As[aoff[m]];
#pragma unroll
    for (int n = 0; n < 2; n++) bv[n] = *(const short8*)&Bs[boff[n]];
#pragma unroll
    for (int m = 0; m < 2; m++)
#pragma unroll
      for (int n = 0; n < 2; n++)
        acc[m][n] = __builtin_amdgcn_mfma_f32_16x16x32_bf16(av[m], bv[n], acc[m][n], 0, 0, 0);
  }
#pragma unroll
  for (int m = 0; m < 2; m++){
    int row0 = m0 + wr*32 + m*16 + g*4;
#pragma unroll
    for (int n = 0; n < 2; n++){
      int col = n0 + wc*32 + n*16 + r15;
#pragma unroll
      for (int r = 0; r < 4; r++){
        float v = acc[m][n][r];
        size_t o = (size_t)(row0 + r)*N + col;
        if (addsrc) v += addsrc[o];
        if (OUTBF) Cb[o] = f2bf(v);
        else       Cf[o] = v;
      }
    }
  }
}

// ===== MoE GEMM1 (gathered rows of h2_bf) -> gu fp32, prefetch =====
__global__ __launch_bounds__(256) void moe_gemm1s(
    const ushort* __restrict__ h2bf, const ushort* __restrict__ wgut,
    const int* __restrict__ ecnt, const int* __restrict__ elist,
    float* __restrict__ gu){
  int e = blockIdx.z;
  int count = ecnt[e];
  int r0 = blockIdx.y*128;
  if (r0 >= count) return;
  __shared__ int rows[128];
  __shared__ __align__(16) ushort As[5120];
  __shared__ __align__(16) ushort Bs[5120];
  int tid = threadIdx.x, lane = tid & 63, w = tid >> 6;
  int n0 = blockIdx.x*128;
  if (tid < 128) rows[tid] = (r0 + tid < count) ? elist[e*2048 + r0 + tid] : -1;
  __syncthreads();
  int wr = w >> 1, wc = w & 1;
  int r15 = lane & 15, g = lane >> 4;
  int srow = tid >> 1, sh = (tid & 1) << 4;
  int ent0 = rows[srow];
  int tok = (ent0 >= 0) ? (ent0 >> 2) : 0;
  const ushort* Ag = h2bf + (size_t)tok*2048 + sh;
  const ushort* Bg = wgut + ((size_t)e*1024 + n0 + srow)*2048 + sh;
  ushort* Asw = &As[srow*40 + sh];
  ushort* Bsw = &Bs[srow*40 + sh];
  int aoff[4], boff[4];
#pragma unroll
  for (int m = 0; m < 4; m++){
    aoff[m] = (wr*64 + m*16 + r15)*40 + g*8;
    boff[m] = (wc*64 + m*16 + r15)*40 + g*8;
  }
  float4v acc[4][4];
#pragma unroll
  for (int i=0;i<4;i++)
#pragma unroll
    for (int j=0;j<4;j++) acc[i][j] = (float4v){0.f,0.f,0.f,0.f};
  short8 a0 = *(const short8*)(Ag);
  short8 a1 = *(const short8*)(Ag + 8);
  short8 b0 = *(const short8*)(Bg);
  short8 b1 = *(const short8*)(Bg + 8);
  for (int kt = 0; kt < 64; kt++){
    __syncthreads();
    *(short8*)Asw = a0; *(short8*)(Asw + 8) = a1;
    *(short8*)Bsw = b0; *(short8*)(Bsw + 8) = b1;
    __syncthreads();
    if (kt < 63){
      int k0 = (kt+1) << 5;
      a0 = *(const short8*)(Ag + k0);
      a1 = *(const short8*)(Ag + k0 + 8);
      b0 = *(const short8*)(Bg + k0);
      b1 = *(const short8*)(Bg + k0 + 8);
    }
    short8 av[4], bv[4];
#pragma unroll
    for (int m = 0; m < 4; m++) av[m] = *(const short8*)&As[aoff[m]];
#pragma unroll
    for (int n = 0; n < 4; n++) bv[n] = *(const short8*)&Bs[boff[n]];
#pragma unroll
    for (int m = 0; m < 4; m++)
#pragma unroll
      for (int n = 0; n < 4; n++)
        acc[m][n] = __builtin_amdgcn_mfma_f32_16x16x32_bf16(av[m], bv[n], acc[m][n], 0, 0, 0);
  }
#pragma unroll
  for (int m = 0; m < 4; m++){
#pragma unroll
    for (int r = 0; r < 4; r++){
      int ent = rows[wr*64 + m*16 + g*4 + r];
      if (ent < 0) continue;
#pragma unroll
      for (int n = 0; n < 4; n++){
        int col = n0 + wc*64 + n*16 + r15;
        gu[(size_t)ent*1024 + col] = acc[m][n][r];
      }
    }
  }
}

// ===== MoE GEMM2: act_bf -> down fp32 (x tw), prefetch =====
__global__ __launch_bounds__(256) void moe_gemm2s(
    const ushort* __restrict__ act, const ushort* __restrict__ wdt,
    const int* __restrict__ ecnt, const int* __restrict__ elist,
    const float* __restrict__ tw, float* __restrict__ down){
  int e = blockIdx.z;
  int count = ecnt[e];
  int r0 = blockIdx.y*128;
  if (r0 >= count) return;
  __shared__ int rows[128];
  __shared__ __align__(16) ushort As[5120];
  __shared__ __align__(16) ushort Bs[5120];
  int tid = threadIdx.x, lane = tid & 63, w = tid >> 6;
  int n0 = blockIdx.x*128;
  if (tid < 128) rows[tid] = (r0 + tid < count) ? elist[e*2048 + r0 + tid] : -1;
  __syncthreads();
  int wr = w >> 1, wc = w & 1;
  int r15 = lane & 15, g = lane >> 4;
  int srow = tid >> 1, sh = (tid & 1) << 4;
  int ent0 = rows[srow];
  int src = (ent0 >= 0) ? ent0 : 0;
  const ushort* Ag = act + (size_t)src*512 + sh;
  const ushort* Bg = wdt + ((size_t)e*2048 + n0 + srow)*512 + sh;
  ushort* Asw = &As[srow*40 + sh];
  ushort* Bsw = &Bs[srow*40 + sh];
  int aoff[4], boff[4];
#pragma unroll
  for (int m = 0; m < 4; m++){
    aoff[m] = (wr*64 + m*16 + r15)*40 + g*8;
    boff[m] = (wc*64 + m*16 + r15)*40 + g*8;
  }
  float4v acc[4][4];
#pragma unroll
  for (int i=0;i<4;i++)
#pragma unroll
    for (int j=0;j<4;j++) acc[i][j] = (float4v){0.f,0.f,0.f,0.f};
  short8 a0 = *(const short8*)(Ag);
  short8 a1 = *(const short8*)(Ag + 8);
  short8 b0 = *(const short8*)(Bg);
  short8 b1 = *(const short8*)(Bg + 8);
  for (int kt = 0; kt < 16; kt++){
    __syncthreads();
    *(short8*)Asw = a0; *(short8*)(Asw + 8) = a1;
    *(short8*)Bsw = b0; *(short8*)(Bsw + 8) = b1;
    __syncthreads();
    if (kt < 15){
      int k0 = (kt+1) << 5;
      a0 = *(const short8*)(Ag + k0);
      a1 = *(const short8*)(Ag + k0 + 8);
      b0 = *(const short8*)(Bg + k0);
      b1 = *(const short8*)(Bg + k0 + 8);
    }
    short8 av[4], bv[4];
#pragma unroll
    for (int m = 0; m < 4; m++) av[m] = *(const short8*)&As[aoff[m]];
#pragma unroll
    for (int n = 0; n < 4; n++) bv[n] = *(const short8*)&Bs[boff[n]];
#pragma unroll
    for (int m = 0; m < 4; m++)
#pragma unroll
      for (int n = 0; n < 4; n++)
        acc[m][n] = __builtin_amdgcn_mfma_f32_16x16x32_bf16(av[m], bv[n], acc[m][n], 0, 0, 0);
  }
#pragma unroll
  for (int m = 0; m < 4; m++){
#pragma unroll
    for (int r = 0; r < 4; r++){
      int ent = rows[wr*64 + m*16 + g*4 + r];
      if (ent < 0) continue;
      float wgt = tw[ent];
#pragma unroll
      for (int n = 0; n < 4; n++){
        int col = n0 + wc*64 + n*16 + r15;
        down[(size_t)ent*2048 + col] = acc[m][n][r]*wgt;
      }
    }
  }
}

// ---------------- top-k (stable ties) ----------------
__global__ __launch_bounds__(256) void topk_kernel(
    const float* __restrict__ scores, int* __restrict__ list, int* __restrict__ cnt){
  int t = blockIdx.x, tid = threadIdx.x;
  if (t < ITOPKk){
    for (int i = tid; i <= t; i += 256) list[(size_t)t*ITOPKk + i] = i;
    if (tid==0) cnt[t] = t+1;
    return;
  }
  int n = t+1;
  const float* row = scores + (size_t)t*2048;
  __shared__ unsigned hist[256];
  __shared__ unsigned sh_prefix, sh_krem;
  __shared__ int scan[256];
  __shared__ int sh_base_sel, sh_base_eq;
  if (tid==0){ sh_prefix = 0u; sh_krem = ITOPKk; }
  __syncthreads();
  for (int level = 3; level >= 0; level--){
    int shift = level*8;
    hist[tid] = 0u; __syncthreads();
    unsigned pfx = sh_prefix;
    for (int s = tid; s < n; s += 256){
      unsigned u = mapf(row[s]);
      bool ok = (level==3) || ((u >> (shift+8)) == pfx);
      if (ok) atomicAdd(&hist[(u >> shift) & 255u], 1u);
    }
    __syncthreads();
    if (tid==0){
      unsigned krem = sh_krem, c = 0u; int bsel = 0;
      for (int b = 255; b >= 0; b--){
        if (c + hist[b] >= krem){ bsel = b; break; }
        c += hist[b];
      }
      sh_prefix = (pfx << 8) | (unsigned)bsel;
      sh_krem = krem - c;
    }
    __syncthreads();
  }
  unsigned uth = sh_prefix; int R = (int)sh_krem;
  if (tid==0){ sh_base_sel = 0; sh_base_eq = 0; }
  __syncthreads();
  for (int c0 = 0; c0 < n; c0 += 256){
    int s = c0 + tid;
    unsigned u = (s < n) ? mapf(row[s]) : 0u;
    int gt = (s < n) && (u > uth);
    int eq = (s < n) && (u == uth);
    scan[tid] = (eq << 16) | gt; __syncthreads();
    for (int off = 1; off < 256; off <<= 1){
      int v = (tid >= off) ? scan[tid-off] : 0; __syncthreads();
      scan[tid] += v; __syncthreads();
    }
    int incl = scan[tid];
    int gt_incl = incl & 0xffff, eq_incl = incl >> 16;
    int gt_excl = gt_incl - gt, eq_excl = eq_incl - eq;
    int tot = scan[255]; int gt_tot = tot & 0xffff, eq_tot = tot >> 16;
    int base_sel = sh_base_sel, base_eq = sh_base_eq;
    int rtake = R - base_eq; if (rtake < 0) rtake = 0;
    bool selected = gt || (eq && eq_excl < rtake);
    int pos = base_sel + gt_excl + min(eq_excl, rtake);
    if (selected) list[(size_t)t*ITOPKk + pos] = s;
    __syncthreads();
    if (tid==0){
      sh_base_sel = base_sel + gt_tot + min(eq_tot, rtake);
      sh_base_eq  = base_eq + eq_tot;
    }
    __syncthreads();
  }
  if (tid==0) cnt[t] = ITOPKk;
}

// ---------------- sparse attention (fp32), XCD-aware ----------------------
// QK: 16 lanes per (s,head) dot -> 4-step width-16 shuffle tree. PV: 4 accs.
#define HG 2
__global__ __launch_bounds__(256) void attn_kernel(
    const float* __restrict__ q, const float* __restrict__ kv,
    const float* __restrict__ kpe,
    const int* __restrict__ list, const int* __restrict__ cnt,
    ushort* __restrict__ at_hi, ushort* __restrict__ at_lo){
  int b = blockIdx.x;
  int g8 = b & 7, t = b >> 3;
  int h0 = g8*HG;
  int tid = threadIdx.x, lane = tid & 63, w = tid >> 6;
  __shared__ int   sl[ITOPKk];
  __shared__ float qs[HG][200];
  __shared__ float lg[HG][ITOPKk];
  __shared__ float redm[4], reds[4];
  __shared__ float4 outp4[8][32];
  int n = cnt[t];
  for (int i = tid; i < n; i += 256) sl[i] = list[(size_t)t*ITOPKk + i];
  for (int i = tid; i < HG*192; i += 256){
    int hh = i/192, d = i - hh*192;
    qs[hh][d] = q[(size_t)t*(NHEAD*QKDd) + (h0+hh)*QKDd + d];
  }
  __syncthreads();
  const float scale = 0.07216878364870323f;
  int half = lane >> 5, l4 = lane & 15, grp = (lane >> 4) & 1;
  float4 qv0 = *(const float4*)&qs[half][l4*8];
  float4 qv1 = *(const float4*)&qs[half][l4*8 + 4];
  float4 qp  = *(const float4*)&qs[half][128 + l4*4];
  size_t koff = (size_t)(h0+half)*256 + (size_t)l4*8;
  size_t poff = (size_t)l4*4;
  for (int i0 = w*4; i0 < n; i0 += 16){
    int idx0 = i0 + grp, idx1 = i0 + grp + 2;
    int e0 = (idx0 < n) ? idx0 : n-1;
    int e1 = (idx1 < n) ? idx1 : n-1;
    int s0 = sl[e0], s1 = sl[e1];
    float4 k00 = *(const float4*)(kv + (size_t)s0*4096 + koff);
    float4 k01 = *(const float4*)(kv + (size_t)s0*4096 + koff + 4);
    float4 p0  = *(const float4*)(kpe + (size_t)s0*64 + poff);
    float4 k10 = *(const float4*)(kv + (size_t)s1*4096 + koff);
    float4 k11 = *(const float4*)(kv + (size_t)s1*4096 + koff + 4);
    float4 p1  = *(const float4*)(kpe + (size_t)s1*64 + poff);
    float d0 = k00.x*qv0.x + k00.y*qv0.y + k00.z*qv0.z + k00.w*qv0.w
             + k01.x*qv1.x + k01.y*qv1.y + k01.z*qv1.z + k01.w*qv1.w
             + p0.x*qp.x + p0.y*qp.y + p0.z*qp.z + p0.w*qp.w;
    float d1 = k10.x*qv0.x + k10.y*qv0.y + k10.z*qv0.z + k10.w*qv0.w
             + k11.x*qv1.x + k11.y*qv1.y + k11.z*qv1.z + k11.w*qv1.w
             + p1.x*qp.x + p1.y*qp.y + p1.z*qp.z + p1.w*qp.w;
#pragma unroll
    for (int off = 8; off > 0; off >>= 1){
      d0 += __shfl_down(d0, off, 16);
      d1 += __shfl_down(d1, off, 16);
    }
    if (l4 == 0){
      if (idx0 < n) lg[half][idx0] = d0*scale;
      if (idx1 < n) lg[half][idx1] = d1*scale;
    }
  }
  __syncthreads();
  int slice = tid & 31, sg = tid >> 5;
  for (int hh = 0; hh < HG; hh++){
    int h = h0 + hh;
    float mx = NEGINF;
    for (int i = tid; i < n; i += 256) mx = fmaxf(mx, lg[hh][i]);
    mx = warp_max(mx);
    if (lane==0) redm[w] = mx;
    __syncthreads();
    mx = fmaxf(fmaxf(redm[0],redm[1]), fmaxf(redm[2],redm[3]));
    float sum = 0.f;
    for (int i = tid; i < n; i += 256){ float p = expf(lg[hh][i]-mx); lg[hh][i] = p; sum += p; }
    sum = warp_sum(sum);
    if (lane==0) reds[w] = sum;
    __syncthreads();
    float inv = 1.f/(reds[0]+reds[1]+reds[2]+reds[3]);
    float4 a0 = {0,0,0,0}, a1 = {0,0,0,0}, a2 = {0,0,0,0}, a3 = {0,0,0,0};
    size_t voff = (size_t)h*256 + 128 + slice*4;
    int i = sg;
    for (; i + 24 < n; i += 32){
      float pA = lg[hh][i];
      float4 vA = *(const float4*)(kv + (size_t)sl[i]*4096 + voff);
      float pB = lg[hh][i+8];
      float4 vB = *(const float4*)(kv + (size_t)sl[i+8]*4096 + voff);
      float pC = lg[hh][i+16];
      float4 vC = *(const float4*)(kv + (size_t)sl[i+16]*4096 + voff);
      float pD = lg[hh][i+24];
      float4 vD = *(const float4*)(kv + (size_t)sl[i+24]*4096 + voff);
      a0.x += pA*vA.x; a0.y += pA*vA.y; a0.z += pA*vA.z; a0.w += pA*vA.w;
      a1.x += pB*vB.x; a1.y += pB*vB.y; a1.z += pB*vB.z; a1.w += pB*vB.w;
      a2.x += pC*vC.x; a2.y += pC*vC.y; a2.z += pC*vC.z; a2.w += pC*vC.w;
      a3.x += pD*vD.x; a3.y += pD*vD.y; a3.z += pD*vD.z; a3.w += pD*vD.w;
    }
    for (; i < n; i += 8){
      float p = lg[hh][i];
      float4 v4 = *(const float4*)(kv + (size_t)sl[i]*4096 + voff);
      a0.x += p*v4.x; a0.y += p*v4.y; a0.z += p*v4.z; a0.w += p*v4.w;
    }
    float4 acc;
    acc.x = (a0.x + a1.x) + (a2.x + a3.x);
    acc.y = (a0.y + a1.y) + (a2.y + a3.y);
    acc.z = (a0.z + a1.z) + (a2.z + a3.z);
    acc.w = (a0.w + a1.w) + (a2.w + a3.w);
    outp4[sg][slice] = acc;
    __syncthreads();
    if (tid < 32){
      float4 r = outp4[0][tid];
#pragma unroll
      for (int gg = 1; gg < 8; gg++){
        float4 o = outp4[gg][tid];
        r.x += o.x; r.y += o.y; r.z += o.z; r.w += o.w;
      }
      r.x *= inv; r.y *= inv; r.z *= inv; r.w *= inv;
      size_t o = (size_t)t*2048 + h*128 + tid*4;
      ushort4 hi4, lo4;
      hi4.x = f2bf(r.x); lo4.x = f2bf(r.x - bf2f(hi4.x));
      hi4.y = f2bf(r.y); lo4.y = f2bf(r.y - bf2f(hi4.y));
      hi4.z = f2bf(r.z); lo4.z = f2bf(r.z - bf2f(hi4.z));
      hi4.w = f2bf(r.w); lo4.w = f2bf(r.w - bf2f(hi4.w));
      *(ushort4*)&at_hi[o] = hi4;
      *(ushort4*)&at_lo[o] = lo4;
    }
    __syncthreads();
  }
}

// ---------------- gate ----------------
__global__ void gate_kernel(const float* __restrict__ glog, float* __restrict__ tw,
                            int* __restrict__ ecnt, int* __restrict__ elist){
  int t = blockIdx.x*256 + threadIdx.x;
  if (t >= T_TOK) return;
  float g[8]; float mx = NEGINF;
  for (int i = 0; i < 8; i++){ g[i] = glog[t*8+i]; mx = fmaxf(mx, g[i]); }
  float s = 0.f;
  for (int i = 0; i < 8; i++){ g[i] = expf(g[i]-mx); s += g[i]; }
  for (int i = 0; i < 8; i++) g[i] /= s;
  bool used[8] = {};
  float tv[4]; int si[4];
  for (int k = 0; k < 4; k++){
    float best = -1.f; int bi = 0;
    for (int i = 0; i < 8; i++) if (!used[i] && g[i] > best){ best = g[i]; bi = i; }
    used[bi] = true; tv[k] = best; si[k] = bi;
  }
  float s4 = tv[0]+tv[1]+tv[2]+tv[3];
  for (int k = 0; k < 4; k++){
    tw[t*4+k] = tv[k]/s4;
    int pos = atomicAdd(&ecnt[si[k]], 1);
    elist[si[k]*2048 + pos] = t*4+k;
  }
}

// ---------------- MoE silu: gu [8192,1024] -> act bf16 [8192,512] ----------------
__global__ __launch_bounds__(256) void silu_moe(const float* __restrict__ gu,
                                                ushort* __restrict__ act){
  int i = blockIdx.x*256 + threadIdx.x;
  if (i >= 8192*128) return;
  int row = i >> 7, jc = i & 127;
  float4 g4 = ((const float4*)(gu + (size_t)row*1024))[jc];
  float4 u4 = ((const float4*)(gu + (size_t)row*1024 + 512))[jc];
  ushort4 o;
  o.x = f2bf(g4.x/(1.f+expf(-g4.x))*u4.x);
  o.y = f2bf(g4.y/(1.f+expf(-g4.y))*u4.y);
  o.z = f2bf(g4.z/(1.f+expf(-g4.z))*u4.z);
  o.w = f2bf(g4.w/(1.f+expf(-g4.w))*u4.w);
  ((ushort4*)(act + (size_t)row*512))[jc] = o;
}

// ---------------- combine: out_final += sum of 4 expert slots ----------------
__global__ __launch_bounds__(256) void moe_combine(const float* __restrict__ down,
                                                   float* __restrict__ outf){
  int t = blockIdx.x;
  size_t base = (size_t)t*4*2048;
  for (int d = threadIdx.x; d < 2048; d += 256){
    float s = down[base+d] + down[base+2048+d] + down[base+4096+d] + down[base+6144+d];
    outf[(size_t)t*2048 + d] += s;
  }
}

// ---------------- shared-expert silu -> bf16 ----------------
__global__ __launch_bounds__(256) void silu_sh(const float* __restrict__ sgu,
                                               ushort* __restrict__ shact){
  int i = blockIdx.x*256 + threadIdx.x;
  if (i >= 2048*256) return;
  int row = i >> 8, jc = i & 255;
  float4 g4 = ((const float4*)(sgu + (size_t)row*2048))[jc];
  float4 u4 = ((const float4*)(sgu + (size_t)row*2048 + 1024))[jc];
  ushort4 o;
  o.x = f2bf(g4.x/(1.f+expf(-g4.x))*u4.x);
  o.y = f2bf(g4.y/(1.f+expf(-g4.y))*u4.y);
  o.z = f2bf(g4.z/(1.f+expf(-g4.z))*u4.z);
  o.w = f2bf(g4.w/(1.f+expf(-g4.w))*u4.w);
  ((ushort4*)(shact + (size_t)row*1024))[jc] = o;
}

// ---------------- host ----------------
extern "C" void kernel_launch(void* const* d_in, const int* in_sizes, int n_in,
                              void* d_out, int out_size, void* d_ws, size_t ws_size,
                              hipStream_t stream){
  const int*   positions  = (const int*)  d_in[0];
  const float* hidden     = (const float*)d_in[1];
  const float* ln1_w      = (const float*)d_in[2];
  const float* ln2_w      = (const float*)d_in[3];
  const float* w_qkv_a    = (const float*)d_in[4];
  const float* q_a_ln_w   = (const float*)d_in[5];
  const float* kv_a_ln_w  = (const float*)d_in[6];
  const float* w_q_b      = (const float*)d_in[7];
  const float* w_kv_b     = (const float*)d_in[8];
  const float* w_o        = (const float*)d_in[9];
  const float* w_idx_k    = (const float*)d_in[10];
  const float* idx_k_ln_w = (const float*)d_in[11];
  const float* idx_k_ln_b = (const float*)d_in[12];
  const float* w_idx_qb   = (const float*)d_in[13];
  const float* w_idx_w    = (const float*)d_in[14];
  const float* w_gate     = (const float*)d_in[15];
  const float* w_moe_gu   = (const float*)d_in[16];
  const float* w_moe_d    = (const float*)d_in[17];
  const float* w_sh_gu    = (const float*)d_in[18];
  const float* w_sh_d     = (const float*)d_in[19];

  float* out_final = (float*)d_out;                       // [T,2048]
  float* residual  = (float*)d_out + (size_t)T_TOK*HIDN;  // [T,2048]

  float* ws = (float*)d_ws;
  // ---- arena (19,005,440 floats) with phase overlays ----
  float* arena   = ws;
  float* qkv_main= arena;                  // [T,2048]  phase1
  float* qkv_pe  = arena + 4194304;        // [T,64]
  float* iscores = arena;                  // [T,T]     overlays qkv (dead)
  float* qbuf    = arena + 4325376;        // [T,16,192]
  float* idx_q   = arena + 10616832;       // [T,16,128] fp32 (pre-rope)
  float* sgu     = arena;                  // phase2 overlays
  float* gu_buf  = arena;
  float* down_buf= arena;
  ushort* act_bf = (ushort*)(arena + 16777216); // [8192,512] bf16
  // qkv_a/idx_k-step split scratch:
  ushort* h_hi  = (ushort*)(arena + 4325376);   // 4,194,304 ush
  ushort* h_lo  = h_hi + 4194304;
  ushort* wqa_hi= (ushort*)(arena + 8519680);   // 4,325,376 ush
  ushort* wqa_lo= wqa_hi + 4325376;
  ushort* wik_hi= (ushort*)(arena + 12845056);  // 262,144 ush
  ushort* wik_lo= wik_hi + 262144;
  // idx_qb-step weight scratch (clobbers h splits after idx_k gemm):
  ushort* wiq_hi= (ushort*)(arena + 4325376);   // 3,145,728 ush
  ushort* wiq_lo= wiq_hi + 3145728;
  // indexer split buffers:
  ushort* ik_hi = (ushort*)(arena + 4325376);   // 262,144 ush (after idx_qb; wiq dead)
  ushort* ik_lo = ik_hi + 262144;
  ushort* iq_hi = (ushort*)(arena + 14811136);  // 4,194,304 ush
  ushort* iq_lo = iq_hi + 4194304;
  // post-topk scratch:
  ushort* s1 = (ushort*)arena;                  // iscores region
  ushort* s2 = (ushort*)(arena + 10616832);     // idx_q/iq region
  // ---- fixed fp32 tail ----
  size_t off = 19005440;
  float* h      = ws + off; off += 4194304;   // [T,2048]
  float* kv     = ws + off; off += 8388608;   // [T,16,256] fp32 (qc-split overlay first)
  float* attnbuf= ws + off; off += 4194304;   // kvc-split overlay / wmd_t
  float* k_pe   = ws + off; off += 131072;
  float* idx_k  = ws + off; off += 262144;    // [T,128] fp32 (pre-LN)
  float* idx_w  = ws + off; off += 32768;
  float* glog   = ws + off; off += 16384;
  float* tw     = ws + off; off += 8192;
  float* ctab   = ws + off; off += 65536;
  float* stab   = ws + off; off += 65536;
  int* list     = (int*)(ws + off);           // [T,512]
  int* cnt      = list + 1048576;
  int* ecnt     = cnt + 2048;
  int* elist    = ecnt + 8;
  off += 1067016;
  // ---- ushort region ----
  ushort* h2_bf   = (ushort*)(ws + off); off += 2097152;
  ushort* shact_bf= (ushort*)(ws + off); off += 1048576;
  ushort* wshgu_t = (ushort*)(ws + off); off += 2097152;
  ushort* wshd_t  = (ushort*)(ws + off); off += 1048576;   // total 43,722,760 floats
  // overlays on dead tail fp32 buffers:
  ushort* qc_hi  = (ushort*)kv;               // dead until kv_b
  ushort* qc_lo  = qc_hi + 3145728;
  ushort* kvc_hi = (ushort*)attnbuf;          // dead until MoE transposes
  ushort* kvc_lo = kvc_hi + 1048576;
  ushort* wmgu_t = (ushort*)kv;
  ushort* wmd_t  = (ushort*)attnbuf;
  size_t total_bytes = off * sizeof(float);
  if (ws_size < total_bytes) return;

  // post-topk scratch assignments:
  ushort* wqbt_hi= s2;
  ushort* wqbt_lo= s2 + 4718592;
  ushort* wkvt_hi= s1;
  ushort* wkvt_lo= s1 + 2097152;
  ushort* at_hi  = s2;                 // attn writes split output here
  ushort* at_lo  = s2 + 4194304;
  ushort* wot_hi = s1;
  ushort* wot_lo = s1 + 4194304;

  // shared-expert weight transposes (consumed after gate)
  transconv<<<dim3(64,64,1), 256, 0, stream>>>(w_sh_gu, wshgu_t, 2048, 2048);
  transconv<<<dim3(64,32,1), 256, 0, stream>>>(w_sh_d,  wshd_t,  1024, 2048);

  rope_table_kernel<<<T_TOK, 32, 0, stream>>>(positions, ctab, stab);
  // ---- rmsnorm + split fused (h fp32 + h_hi/h_lo) ----
  rmsnorm_both<<<T_TOK, 256, 0, stream>>>(hidden, HIDN, 0, ln1_w, h, h_hi, h_lo, HIDN, HIDN);
  // ---- qkv_a via split-bf16 MFMA (2048 cols) + fp32 (pe 64 cols) ----
  transconv_split<<<dim3(66,64), 256, 0, stream>>>(w_qkv_a, wqa_hi, wqa_lo, 2048, 2112);
  gemm_b3<<<dim3(32,32), 256, 0, stream>>>(h_hi, h_lo, wqa_hi, wqa_lo, qkv_main, nullptr, 2048, 2048);
  gemm_f32<<<dim3(1,32), 256, 0, stream>>>(h, HIDN, w_qkv_a + 2048, 2112, qkv_pe, 64, nullptr, 0, T_TOK, 64, HIDN, 1.f);
  // ---- fused rmsnorm -> split for q_c / kv_c ----
  rmsnorm_split<<<T_TOK, 256, 0, stream>>>(qkv_main, 2048, 0,    q_a_ln_w,  qc_hi,  qc_lo,  QLRr,  QLRr);
  rmsnorm_split<<<T_TOK, 256, 0, stream>>>(qkv_main, 2048, QLRr, kv_a_ln_w, kvc_hi, kvc_lo, KVLRr, KVLRr);
  rope_kpe_kernel<<<T_TOK, 32, 0, stream>>>(qkv_pe, ctab, stab, k_pe);
  // ---- idx_k via split-bf16 MFMA (fp32 pre-LN out) ----
  transconv_split<<<dim3(4,64), 256, 0, stream>>>(w_idx_k, wik_hi, wik_lo, 2048, 128);
  gemm_b3<<<dim3(2,32), 256, 0, stream>>>(h_hi, h_lo, wik_hi, wik_lo, idx_k, nullptr, 128, 2048);
  // ---- idx_qb via split-bf16 MFMA ----
  transconv_split<<<dim3(64,48), 256, 0, stream>>>(w_idx_qb, wiq_hi, wiq_lo, 1536, 2048);
  gemm_b3<<<dim3(32,32), 256, 0, stream>>>(qc_hi, qc_lo, wiq_hi, wiq_lo, idx_q, nullptr, 2048, 1536);
  // ---- fused rope -> split for idx_q ----
  rope_idxq_split<<<T_TOK, 256, 0, stream>>>(idx_q, ctab, stab, iq_hi, iq_lo);
  // ---- fused LN+rope -> split for idx_k (wiq dead now) ----
  ln_rope_idxk_split<<<T_TOK, 128, 0, stream>>>(idx_k, idx_k_ln_w, idx_k_ln_b, ctab, stab, ik_hi, ik_lo);
  // ---- idx_w (tiny fp32) ----
  gemm_f32<<<dim3(1,32), 256, 0, stream>>>(h, HIDN, w_idx_w, INHh, idx_w, INHh, nullptr, 0, T_TOK, INHh, HIDN, 0.02209708691207961f);
  // ---- iscores via split-bf16 MFMA (triangular, 64x64) ----
  iscores_b3<<<dim3(32,32), 256, 0, stream>>>(iq_hi, iq_lo, ik_hi, ik_lo, idx_w, iscores);
  topk_kernel<<<T_TOK, 256, 0, stream>>>(iscores, list, cnt);
  // ---- q_b via split-bf16 MFMA ----
  transconv_split<<<dim3(96,48), 256, 0, stream>>>(w_q_b, wqbt_hi, wqbt_lo, 1536, 3072);
  gemm_b3<<<dim3(48,32), 256, 0, stream>>>(qc_hi, qc_lo, wqbt_hi, wqbt_lo, qbuf, nullptr, 3072, 1536);
  rope_q_kernel<<<T_TOK, 256, 0, stream>>>(qbuf, ctab, stab);
  // ---- kv_b via split-bf16 MFMA (qc splits dead -> kv fp32 reuse OK) ----
  transconv_split<<<dim3(128,16), 256, 0, stream>>>(w_kv_b, wkvt_hi, wkvt_lo, 512, 4096);
  gemm_b3<<<dim3(64,32), 256, 0, stream>>>(kvc_hi, kvc_lo, wkvt_hi, wkvt_lo, kv, nullptr, 4096, 512);
  // ---- attention (writes split hi/lo output directly) ----
  attn_kernel<<<T_TOK*(NHEAD/HG), 256, 0, stream>>>(qbuf, kv, k_pe, list, cnt, at_hi, at_lo);
  // ---- w_o via split-bf16 MFMA (+hidden -> residual) ----
  transconv_split<<<dim3(64,64), 256, 0, stream>>>(w_o, wot_hi, wot_lo, 2048, 2048);
  gemm_b3<<<dim3(32,32), 256, 0, stream>>>(at_hi, at_lo, wot_hi, wot_lo, residual, hidden, 2048, 2048);
  // kv/attnbuf now dead -> MoE weight transposes into their space
  transconv<<<dim3(32,64,8), 256, 0, stream>>>(w_moe_gu, wmgu_t, 2048, 1024);
  transconv<<<dim3(64,16,8), 256, 0, stream>>>(w_moe_d,  wmd_t,  512,  2048);
  // ---- rmsnorm2 + bf16 fused (h fp32 + h2_bf) ----
  rmsnorm_bfo<<<T_TOK, 256, 0, stream>>>(residual, HIDN, 0, ln2_w, h, h2_bf, HIDN, HIDN);
  gemm_f32<<<dim3(1,32), 256, 0, stream>>>(h, HIDN, w_gate, NEXP, glog, NEXP, nullptr, 0, T_TOK, NEXP, HIDN, 1.f);
  hipMemsetAsync(ecnt, 0, NEXP*sizeof(int), stream);
  gate_kernel<<<8, 256, 0, stream>>>(glog, tw, ecnt, elist);
  // shared expert (arena as sgu)
  gemm_bf16s<0><<<dim3(32,32), 256, 0, stream>>>(h2_bf, wshgu_t, sgu, nullptr, nullptr, 2048, 2048);
  silu_sh<<<2048, 256, 0, stream>>>(sgu, shact_bf);
  gemm_bf16s<0><<<dim3(32,32), 256, 0, stream>>>(shact_bf, wshd_t, out_final, nullptr, nullptr, 2048, 1024);
  // MoE (arena as gu -> act_bf -> down)
  moe_gemm1s<<<dim3(8, 16, NEXP), 256, 0, stream>>>(h2_bf, wmgu_t, ecnt, elist, gu_buf);
  silu_moe<<<4096, 256, 0, stream>>>(gu_buf, act_bf);
  moe_gemm2s<<<dim3(16, 16, NEXP), 256, 0, stream>>>(act_bf, wmd_t, ecnt, elist, tw, down_buf);
  moe_combine<<<T_TOK, 256, 0, stream>>>(down_buf, out_final);
  (void)in_sizes; (void)n_in; (void)out_size;
}